// Round 12
// baseline (385.829 us; speedup 1.0000x reference)
//
#include <hip/hip_runtime.h>
#include <hip/hip_bf16.h>
#include <hip/hip_fp16.h>

// Problem constants
#define NB   2
#define NC   96
#define NW   128
#define NPIX 16384   // 128*128
#define NHD  8
#define CHD  12
#define HIDC 255
#define H2C  510
#define H4C  1020

typedef __hip_bfloat16 bf16;
typedef unsigned short u16;
typedef unsigned int   u32;
typedef __half2 h2t;

typedef __attribute__((ext_vector_type(8))) __bf16 bfrag;
typedef __attribute__((ext_vector_type(4))) float  ffrag;

__device__ __forceinline__ float bfu(u16 u)  { return __uint_as_float(((u32)u) << 16); }
__device__ __forceinline__ float bflo(u32 u) { return __uint_as_float(u << 16); }
__device__ __forceinline__ float bfhi(u32 u) { return __uint_as_float(u & 0xffff0000u); }
__device__ __forceinline__ u16 f2u16(float a) {
    bf16 x = __float2bfloat16(a); return *(u16*)&x;
}
__device__ __forceinline__ u32 packbf(float a, float b) {
    return (u32)f2u16(a) | ((u32)f2u16(b) << 16);
}
__device__ __forceinline__ uint4 pack8(const float o[8]) {
    uint4 r; r.x = packbf(o[0], o[1]); r.y = packbf(o[2], o[3]);
    r.z = packbf(o[4], o[5]); r.w = packbf(o[6], o[7]); return r;
}

// half2 bit helpers
__device__ __forceinline__ h2t H2u(u32 v) { return __builtin_bit_cast(h2t, v); }
__device__ __forceinline__ u32 U32h(h2t v) { return __builtin_bit_cast(u32, v); }
// packed fp16 relu: single v_pk_max_f16 (inline asm: fp16 __hmax2 overload is
// ambiguous/bf16-routed on ROCm 7.2 with both fp16+bf16 headers included).
__device__ __forceinline__ h2t relu2(h2t v) {
    u32 r, u = U32h(v);
    asm("v_pk_max_f16 %0, %1, 0" : "=v"(r) : "v"(u));
    return H2u(r);
}
// splat low/high half of a packed fp16 pair held in a VGPR u32.
__device__ __forceinline__ h2t wtap(const h2t* a, int idx) {
    u32 u = U32h(a[idx >> 1]);
    u32 r = (idx & 1) ? ((u & 0xFFFF0000u) | (u >> 16)) : ((u << 16) | (u & 0xFFFFu));
    return H2u(r);
}

// ================= streaming FFN midsection =================
// One wave = (group g of 4 channels, 32-row strip, batch). R8 config:
// strip 32, VGPR packed weights, depth-2 row prefetch, unroll 3. 86-93us.
// NO waves/EU bound (R5: (64,4) -> 64-VGPR clamp -> 1GB spill).
struct Trip { h2t L, C, R; };
__device__ __forceinline__ Trip shift3(h2t c2, bool repl, int lane) {
    u32 d = U32h(c2);
    u32 up = (u32)__shfl_up((int)d, 1);
    u32 dn = (u32)__shfl_down((int)d, 1);
    if (lane == 0)  up = repl ? (d << 16) : 0u;
    if (lane == 63) dn = repl ? (d >> 16) : 0u;
    Trip t; t.C = c2;
    t.L = H2u((up >> 16) | (d << 16));
    t.R = H2u((d >> 16) | (dn << 16));
    return t;
}
__device__ __forceinline__ h2t ldrow2(const u16* base, int row, int lane) {
    return ((unsigned)row < 128u) ? *(const h2t*)(base + row * NW + lane * 2) : H2u(0u);
}
#define CONV3(W, c, T, Pa, Pb, Pc)                                             \
    Pc = __hfma2(wtap(W, (c)*9+0), T.L, __hfma2(wtap(W, (c)*9+1), T.C,         \
         __hfma2(wtap(W, (c)*9+2), T.R, Pc)));                                 \
    Pb = __hfma2(wtap(W, (c)*9+3), T.L, __hfma2(wtap(W, (c)*9+4), T.C,         \
         __hfma2(wtap(W, (c)*9+5), T.R, Pb)));                                 \
    Pa = __hfma2(wtap(W, (c)*9+6), T.L, __hfma2(wtap(W, (c)*9+7), T.C,         \
         __hfma2(wtap(W, (c)*9+8), T.R, Pa)));

__global__ __launch_bounds__(64) void ffnstream_kernel(
    const u16* __restrict__ yi, const float* __restrict__ main_w,
    const float* __restrict__ lp_w, const float* __restrict__ hp_w,
    const float* __restrict__ ld_w, const float* __restrict__ hd_w,
    u16* __restrict__ cat) {
    const int lane = threadIdx.x;
    const int g = blockIdx.y;
    const int R0 = blockIdx.x * 32, R1 = R0 + 32;
    const int L0 = max(R0 - 2, 0), L1 = min(R1 + 1, 127);
    const int P0 = max(R0 - 1, 0), P1 = min(R1, 127);
    const u16* yib = yi + (size_t)blockIdx.z * H2C * NPIX;
    u16* catb = cat + (size_t)blockIdx.z * H2C * NPIX;
    const u16* s0p = yib + (size_t)(2 * g) * NPIX;
    const u16* s1p = yib + (size_t)(2 * g + 1) * NPIX;

    h2t wm[18], wl[18], wh[18], wd[18], we[18];
    {
        const float* pm = main_w + 36 * g;
        const float* pl = lp_w + 36 * g;
        const float* ph = hp_w + 36 * g;
        const float* pd = ld_w + 36 * g;
        const float* pe = hd_w + 36 * g;
        #pragma unroll
        for (int k = 0; k < 18; ++k) {
            wm[k] = __halves2half2(__float2half(pm[2*k]), __float2half(pm[2*k+1]));
            wl[k] = __halves2half2(__float2half(pl[2*k]), __float2half(pl[2*k+1]));
            wh[k] = __halves2half2(__float2half(ph[2*k]), __float2half(ph[2*k+1]));
            wd[k] = __halves2half2(__float2half(pd[2*k]), __float2half(pd[2*k+1]));
            we[k] = __halves2half2(__float2half(pe[2*k]), __float2half(pe[2*k+1]));
        }
    }
    const h2t z = H2u(0u);
    const __half k9h = __float2half(1.f / 9.f);
    const h2t k9 = __halves2half2(k9h, k9h);

    h2t ymP0[4], ymP1[4], ymP2[4];
    h2t ymRa[4], ymRb[4], ymRc[4];
    h2t lpP0[4], lpP1[4], lpP2[4];
    h2t hpP0[4], hpP1[4], hpP2[4];
    h2t cd0 = z, cd1 = z, cd2 = z;
    h2t ce0 = z, ce1 = z, ce2 = z;
    #pragma unroll
    for (int c = 0; c < 4; ++c) {
        ymP0[c] = ymP1[c] = ymP2[c] = z;
        ymRa[c] = ymRb[c] = ymRc[c] = z;
        lpP0[c] = lpP1[c] = lpP2[c] = z;
        hpP0[c] = hpP1[c] = hpP2[c] = z;
    }

    const int ys = max(R0 - 3, 0) - 1;
    const int ye = R1 + 3;
    h2t cur0 = ldrow2(s0p, ys, lane),     cur1 = ldrow2(s1p, ys, lane);
    h2t nx10 = ldrow2(s0p, ys + 1, lane), nx11 = ldrow2(s1p, ys + 1, lane);
    #pragma unroll 3
    for (int yy = ys; yy <= ye; ++yy) {
        h2t nx20 = ldrow2(s0p, yy + 2, lane), nx21 = ldrow2(s1p, yy + 2, lane);
        // A
        {
            Trip t0 = shift3(cur0, false, lane);
            Trip t1 = shift3(cur1, false, lane);
            CONV3(wm, 0, t0, ymP0[0], ymP1[0], ymP2[0]);
            CONV3(wm, 1, t0, ymP0[1], ymP1[1], ymP2[1]);
            CONV3(wm, 2, t1, ymP0[2], ymP1[2], ymP2[2]);
            CONV3(wm, 3, t1, ymP0[3], ymP1[3], ymP2[3]);
        }
        // B
        #pragma unroll
        for (int c = 0; c < 4; ++c) {
            h2t n = relu2(ymP0[c]);
            ymRc[c] = ymRb[c]; ymRb[c] = ymRa[c]; ymRa[c] = n;
            ymP0[c] = ymP1[c]; ymP1[c] = ymP2[c]; ymP2[c] = z;
        }
        // C
        int y_l = yy - 2;
        if (y_l >= L0 && y_l <= L1) {
            #pragma unroll
            for (int c = 0; c < 4; ++c) {
                h2t top = (y_l == 0)   ? ymRb[c] : ymRc[c];
                h2t bot = (y_l == 127) ? ymRb[c] : ymRa[c];
                h2t vs = __hadd2(__hadd2(top, ymRb[c]), bot);
                Trip tv = shift3(vs, true, lane);
                h2t l  = __hmul2(__hadd2(__hadd2(tv.L, tv.C), tv.R), k9);
                h2t hb = __hsub2(ymRb[c], l);
                Trip tl = shift3(l, false, lane);
                CONV3(wl, c, tl, lpP0[c], lpP1[c], lpP2[c]);
                Trip th = shift3(hb, false, lane);
                CONV3(wh, c, th, hpP0[c], hpP1[c], hpP2[c]);
            }
        }
        // E
        int y_p = yy - 3;
        {
            h2t lpN[4], hpN[4];
            #pragma unroll
            for (int c = 0; c < 4; ++c) {
                lpN[c] = relu2(lpP0[c]); hpN[c] = relu2(hpP0[c]);
                lpP0[c] = lpP1[c]; lpP1[c] = lpP2[c]; lpP2[c] = z;
                hpP0[c] = hpP1[c]; hpP1[c] = hpP2[c]; hpP2[c] = z;
            }
            if (y_p >= P0 && y_p <= P1) {
                #pragma unroll
                for (int c = 0; c < 4; ++c) {
                    bool low = (4 * g + c) < H2C;
                    h2t sld = low ? lpN[c] : hpN[c];
                    h2t shd = low ? hpN[c] : lpN[c];
                    Trip ts = shift3(sld, false, lane);
                    CONV3(wd, c, ts, cd0, cd1, cd2);
                    Trip tu = shift3(shd, false, lane);
                    CONV3(we, c, tu, ce0, ce1, ce2);
                }
            }
        }
        // F
        int y_c = yy - 4;
        if (y_c >= R0 && y_c < R1) {
            float a0 = fmaxf(__low2float(cd0), 0.f), a1 = fmaxf(__high2float(cd0), 0.f);
            float b0 = fmaxf(__low2float(ce0), 0.f), b1 = fmaxf(__high2float(ce0), 0.f);
            *(u32*)(catb + (size_t)g * NPIX + y_c * NW + lane * 2) = packbf(a0, a1);
            *(u32*)(catb + (size_t)(HIDC + g) * NPIX + y_c * NW + lane * 2) = packbf(b0, b1);
        }
        cd0 = cd1; cd1 = cd2; cd2 = z;
        ce0 = ce1; ce1 = ce2; ce2 = z;
        cur0 = nx10; cur1 = nx11;
        nx10 = nx20; nx11 = nx21;
    }
}

// ================= MFMA GEMM for 1x1 convs, M-tile = 128 =================
// OFMT: 0 = f32 out, 1 = bf16 out, 2 = fp16 out
// M-tile 128 (two 64-row halves per block): halves the per-m-block B-panel
// re-reads (qkv 5->3, in 8->4, proj/out 2->1 blocks) — B re-read traffic was
// L3-absorbed (invisible in FETCH_SIZE) but still ~2TB/s-class time.
// LNF: fuse channel-LayerNorm into B staging (fp32 xf -> per-pixel mu/inv
// over 96 channels -> bf16 once; identical rounding to separate ln kernel).
template <typename TOut, bool RES, int OFMT, bool LNF = false>
__global__ __launch_bounds__(256) void gemm1x1_kernel(
    const u16* __restrict__ Bm, const float* __restrict__ Am,
    const float* __restrict__ res, TOut* __restrict__ Cm,
    int M, int K, size_t strideB, size_t strideC, size_t strideA,
    const float* __restrict__ xf, const float* __restrict__ lng,
    const float* __restrict__ lnb) {
    __shared__ u16 Ash[128 * 40];
    __shared__ u16 Bsh[128 * 40];
    __shared__ float lmu[128], linv[128];
    __shared__ float sred[2][128], qred[2][128];
    const u16* Bz = Bm + (size_t)blockIdx.z * strideB;
    const float* Az = Am + (size_t)blockIdx.z * strideA;
    const float* xz = LNF ? (xf + (size_t)blockIdx.z * NC * NPIX) : nullptr;
    int n0 = blockIdx.x * 128;
    int m0 = blockIdx.y * 128;
    int tid = threadIdx.x;
    int w = tid >> 6, l15 = tid & 15, q = (tid & 63) >> 4;
    int amm = tid >> 2, akc = (tid & 3) * 8;
    int bkk = tid >> 3, bs0 = tid & 7;

    if constexpr (LNF) {
        // per-pixel LN stats over the 96 channels of this 128-px tile
        int p = tid & 127, hh = tid >> 7;
        float s = 0.f, s2 = 0.f;
        #pragma unroll
        for (int c = 0; c < 48; ++c) {
            float v = xz[(size_t)(hh * 48 + c) * NPIX + n0 + p];
            s += v; s2 += v * v;
        }
        sred[hh][p] = s; qred[hh][p] = s2;
        __syncthreads();
        if (tid < 128) {
            float S = sred[0][tid] + sred[1][tid];
            float Q = qred[0][tid] + qred[1][tid];
            float m = S * (1.f / NC);
            float va = Q * (1.f / NC) - m * m;
            lmu[tid] = m; linv[tid] = rsqrtf(va + 1e-5f);
        }
        __syncthreads();
    }

    ffrag acc[2][8];
    #pragma unroll
    for (int mt = 0; mt < 2; ++mt)
        #pragma unroll
        for (int nt = 0; nt < 8; ++nt)
            #pragma unroll
            for (int e = 0; e < 4; ++e) acc[mt][nt][e] = 0.f;

    for (int k0 = 0; k0 < K; k0 += 32) {
        // A staging: 128 rows x 32 cols bf16, two 64-row halves
        #pragma unroll
        for (int half = 0; half < 2; ++half) {
            int gm = m0 + half * 64 + amm;
            float f[8];
            #pragma unroll
            for (int e = 0; e < 8; ++e) {
                int gk = k0 + akc + e;
                f[e] = (gm < M && gk < K) ? Az[(size_t)gm * K + gk] : 0.f;
            }
            u32* dst = (u32*)&Ash[(half * 64 + amm) * 40 + akc];
            #pragma unroll
            for (int e = 0; e < 4; ++e) dst[e] = packbf(f[2 * e], f[2 * e + 1]);
        }
        if constexpr (LNF) {
            int gk = k0 + bkk;           // K == 96 exactly, always in range
            const float* src = xz + (size_t)gk * NPIX + n0;
            float gc = lng[gk], bc = lnb[gk];
            #pragma unroll
            for (int pass = 0; pass < 2; ++pass) {
                int nn = (bs0 + pass * 8) * 8;
                float4 f0 = *(const float4*)(src + nn);
                float4 f1 = *(const float4*)(src + nn + 4);
                float f[8] = {f0.x, f0.y, f0.z, f0.w, f1.x, f1.y, f1.z, f1.w};
                #pragma unroll
                for (int e = 0; e < 8; ++e) {
                    float nv = (f[e] - lmu[nn + e]) * linv[nn + e] * gc + bc;
                    Bsh[(nn + e) * 40 + bkk] = f2u16(nv);
                }
            }
        } else {
            int gk = k0 + bkk;
            bool ok = gk < K;
            const u16* src = Bz + (size_t)gk * NPIX + n0;
            #pragma unroll
            for (int pass = 0; pass < 2; ++pass) {
                int nn = (bs0 + pass * 8) * 8;
                if (ok) {
                    uint4 v = *(const uint4*)(src + nn);
                    Bsh[(nn + 0) * 40 + bkk] = (u16)(v.x & 0xffff);
                    Bsh[(nn + 1) * 40 + bkk] = (u16)(v.x >> 16);
                    Bsh[(nn + 2) * 40 + bkk] = (u16)(v.y & 0xffff);
                    Bsh[(nn + 3) * 40 + bkk] = (u16)(v.y >> 16);
                    Bsh[(nn + 4) * 40 + bkk] = (u16)(v.z & 0xffff);
                    Bsh[(nn + 5) * 40 + bkk] = (u16)(v.z >> 16);
                    Bsh[(nn + 6) * 40 + bkk] = (u16)(v.w & 0xffff);
                    Bsh[(nn + 7) * 40 + bkk] = (u16)(v.w >> 16);
                } else {
                    #pragma unroll
                    for (int e = 0; e < 8; ++e) Bsh[(nn + e) * 40 + bkk] = 0;
                }
            }
        }
        __syncthreads();
        bfrag af0 = *(const bfrag*)&Ash[(w * 16 + l15) * 40 + q * 8];
        bfrag af1 = *(const bfrag*)&Ash[(64 + w * 16 + l15) * 40 + q * 8];
        #pragma unroll
        for (int nt = 0; nt < 8; ++nt) {
            bfrag bf = *(const bfrag*)&Bsh[(nt * 16 + l15) * 40 + q * 8];
            acc[0][nt] = __builtin_amdgcn_mfma_f32_16x16x32_bf16(af0, bf, acc[0][nt], 0, 0, 0);
            acc[1][nt] = __builtin_amdgcn_mfma_f32_16x16x32_bf16(af1, bf, acc[1][nt], 0, 0, 0);
        }
        __syncthreads();
    }
    TOut* Cz = Cm + (size_t)blockIdx.z * strideC;
    const float* rz = res + (RES ? (size_t)blockIdx.z * strideC : 0);
    #pragma unroll
    for (int mt = 0; mt < 2; ++mt) {
        int mrow = m0 + mt * 64 + w * 16 + q * 4;
        #pragma unroll
        for (int nt = 0; nt < 8; ++nt) {
            int col = n0 + nt * 16 + l15;
            #pragma unroll
            for (int r = 0; r < 4; ++r) {
                int row = mrow + r;
                if (row < M) {
                    float v = acc[mt][nt][r];
                    if (RES) v += rz[(size_t)row * NPIX + col];
                    if constexpr (OFMT == 0) {
                        ((float*)Cz)[(size_t)row * NPIX + col] = v;
                    } else if constexpr (OFMT == 1) {
                        ((u16*)Cz)[(size_t)row * NPIX + col] = f2u16(v);
                    } else {
                        __half hh = __float2half(v);
                        ((u16*)Cz)[(size_t)row * NPIX + col] = __builtin_bit_cast(u16, hh);
                    }
                }
            }
        }
    }
}

// load a 1x10 window row (8 aligned + 2 halo) with zero padding (global memory)
__device__ __forceinline__ void load_row_zpad(const u16* ib, int iy, int x0, float a[10]) {
    if (iy < 0 || iy >= NW) {
        #pragma unroll
        for (int k = 0; k < 10; ++k) a[k] = 0.f;
        return;
    }
    const u16* rp = ib + iy * NW;
    uint4 v = *(const uint4*)(rp + x0);
    a[1]=bflo(v.x); a[2]=bfhi(v.x); a[3]=bflo(v.y); a[4]=bfhi(v.y);
    a[5]=bflo(v.z); a[6]=bfhi(v.z); a[7]=bflo(v.w); a[8]=bfhi(v.w);
    a[0] = (x0 > 0)   ? bfu(rp[x0 - 1]) : 0.f;
    a[9] = (x0 < 120) ? bfu(rp[x0 + 8]) : 0.f;
}

// ---------------- depthwise 3x3 (qkv), zero pad, 4 rows x 8 px/thread -------
// Fused qknorm: channels < 192 (q,k) accumulate sum-of-squares of the conv
// output (pre-bf16-rounding, sub-ulp diff) into sqsum[b*192+oc] via one
// atomicAdd per block (2 blocks/channel).
template <bool RELU>
__global__ __launch_bounds__(256) void dwconv3x3_kernel(
    const u16* __restrict__ in, const float* __restrict__ w,
    u16* __restrict__ out, int CHN, int ICN, int idiv,
    float* __restrict__ sqsum) {
    int id = blockIdx.x * 256 + threadIdx.x;   // 0..511
    int ty = id >> 4, tx = id & 15;
    int y0 = ty * 4, x0 = tx * 8;
    int b = blockIdx.y / CHN, oc = blockIdx.y % CHN;
    int ic = oc / idiv;
    const u16* ib = in + ((size_t)b * ICN + ic) * NPIX;
    float a[6][10];
    #pragma unroll
    for (int k = 0; k < 6; ++k) load_row_zpad(ib, y0 - 1 + k, x0, a[k]);
    const float* wr = w + (size_t)oc * 9;
    float w9[9];
    #pragma unroll
    for (int k = 0; k < 9; ++k) w9[k] = wr[k];
    u16* ob = out + ((size_t)b * CHN + oc) * NPIX + y0 * NW + x0;
    float s2 = 0.f;
    #pragma unroll
    for (int jr = 0; jr < 4; ++jr) {
        float o[8];
        #pragma unroll
        for (int j = 0; j < 8; ++j) {
            float s = 0.f;
            #pragma unroll
            for (int r = 0; r < 3; ++r)
                #pragma unroll
                for (int kx = 0; kx < 3; ++kx)
                    s += w9[r * 3 + kx] * a[jr + r][j + kx];
            o[j] = RELU ? fmaxf(s, 0.f) : s;
            s2 += o[j] * o[j];
        }
        *(uint4*)(ob + jr * NW) = pack8(o);
    }
    if (oc < 192) {   // block-uniform branch
        #pragma unroll
        for (int off = 32; off > 0; off >>= 1) s2 += __shfl_down(s2, off, 64);
        __shared__ float prt[4];
        int wid = threadIdx.x >> 6;
        if ((threadIdx.x & 63) == 0) prt[wid] = s2;
        __syncthreads();
        if (threadIdx.x == 0)
            atomicAdd(&sqsum[b * 192 + oc], prt[0] + prt[1] + prt[2] + prt[3]);
    }
}

// ---------------- raw attn dots, 4-way pixel split + atomicAdd ----------------
__global__ __launch_bounds__(256) void attn_kernel(
    const u16* __restrict__ qkv2, float* __restrict__ attn_raw) {
    int blk = blockIdx.y;  // ((b*NHD+h)*CHD+i)
    int slice = blockIdx.x;
    int i = blk % CHD; int h = (blk / CHD) % NHD; int b = blk / (CHD * NHD);
    const u16* q = qkv2 + ((size_t)b * 288 + h * CHD + i) * NPIX;
    const u16* k = qkv2 + ((size_t)b * 288 + 96 + h * CHD) * NPIX;
    float acc[CHD];
    #pragma unroll
    for (int j = 0; j < CHD; ++j) acc[j] = 0.f;
    int p0 = slice * 4096;
    #pragma unroll
    for (int it = 0; it < 2; ++it) {
        int p = p0 + it * 2048 + threadIdx.x * 8;
        uint4 qv = *(const uint4*)(q + p);
        float qf[8];
        qf[0]=bflo(qv.x); qf[1]=bfhi(qv.x); qf[2]=bflo(qv.y); qf[3]=bfhi(qv.y);
        qf[4]=bflo(qv.z); qf[5]=bfhi(qv.z); qf[6]=bflo(qv.w); qf[7]=bfhi(qv.w);
        #pragma unroll
        for (int j = 0; j < CHD; ++j) {
            uint4 kv = *(const uint4*)(k + (size_t)j * NPIX + p);
            float s = qf[0]*bflo(kv.x) + qf[1]*bfhi(kv.x) + qf[2]*bflo(kv.y) + qf[3]*bfhi(kv.y)
                    + qf[4]*bflo(kv.z) + qf[5]*bfhi(kv.z) + qf[6]*bflo(kv.w) + qf[7]*bfhi(kv.w);
            acc[j] += s;
        }
    }
    __shared__ float part[4][CHD];
    int wid = threadIdx.x >> 6, lane = threadIdx.x & 63;
    #pragma unroll
    for (int j = 0; j < CHD; ++j) {
        float v = acc[j];
        #pragma unroll
        for (int off = 32; off > 0; off >>= 1) v += __shfl_down(v, off, 64);
        if (lane == 0) part[wid][j] = v;
    }
    __syncthreads();
    if (threadIdx.x < CHD) {
        int j = threadIdx.x;
        float d = part[0][j] + part[1][j] + part[2][j] + part[3][j];
        atomicAdd(&attn_raw[(size_t)blk * CHD + j], d);
    }
}

// ---------------- STS + W-mix fused ----------------
// sclr holds raw per-channel sum-of-squares (from dwconv); convert to
// reciprocal norms in LDS, scale raw dots, thresholds, 4-way softmax mix
// -> attnc (LDS only), then W = proj @ attnc (av+proj fusion).
__global__ __launch_bounds__(256) void sts_kernel(
    const float* __restrict__ attn, const float* __restrict__ sclr,
    const float* __restrict__ temp, const float* __restrict__ tw,
    const float* __restrict__ w1, const float* __restrict__ b1,
    const float* __restrict__ w2, const float* __restrict__ b2,
    const float* __restrict__ proj_w, float* __restrict__ Wm) {
    int b = blockIdx.x;
    __shared__ float sat[NHD * CHD * CHD];
    __shared__ float sac[NHD * CHD * CHD];
    __shared__ float srs[192];
    __shared__ float pavg[NHD * CHD];
    __shared__ float avg[NHD];
    __shared__ float thr[4][NHD];
    if (threadIdx.x < 192) {
        float r = sclr[b * 192 + threadIdx.x];
        srs[threadIdx.x] = 1.f / fmaxf(sqrtf(r), 1e-12f);
    }
    __syncthreads();
    for (int idx = threadIdx.x; idx < NHD * CHD * CHD; idx += 256) {
        int h = idx / (CHD * CHD); int r = idx % (CHD * CHD);
        int i = r / CHD, j = r % CHD;
        sat[idx] = attn[(size_t)b * NHD * CHD * CHD + idx]
                 * srs[h * CHD + i] * srs[96 + h * CHD + j] * temp[h];
    }
    __syncthreads();
    if (threadIdx.x < NHD * CHD) {
        float s = 0.f;
        const float* row = sat + threadIdx.x * CHD;
        #pragma unroll
        for (int j = 0; j < CHD; ++j) s += fabsf(row[j]);
        pavg[threadIdx.x] = s;
    }
    __syncthreads();
    if (threadIdx.x < NHD) {
        float s = 0.f;
        #pragma unroll
        for (int i = 0; i < CHD; ++i) s += pavg[threadIdx.x * CHD + i];
        avg[threadIdx.x] = s * (1.f / (CHD * CHD));
    }
    __syncthreads();
    if (threadIdx.x < 4) {
        int s = threadIdx.x;
        float t1[NHD];
        for (int hp = 0; hp < NHD; ++hp) {
            float u = b1[s * NHD + hp];
            for (int h = 0; h < NHD; ++h) u += avg[h] * w1[s * 64 + hp * NHD + h];
            t1[hp] = fmaxf(u, 0.f);
        }
        for (int hp = 0; hp < NHD; ++hp) {
            float u = b2[s * NHD + hp];
            for (int h = 0; h < NHD; ++h) u += t1[h] * w2[s * 64 + hp * NHD + h];
            float gg = 1.f / (1.f + expf(-u));
            thr[s][hp] = avg[hp] * gg;
        }
    }
    __syncthreads();
    if (threadIdx.x < NHD * CHD) {
        int h = threadIdx.x / CHD, i = threadIdx.x % CHD;
        const float* arow = sat + (h * CHD + i) * CHD;
        float acc[CHD];
        #pragma unroll
        for (int j = 0; j < CHD; ++j) acc[j] = 0.f;
        for (int s = 0; s < 4; ++s) {
            float comp[CHD]; float m = -1e30f;
            #pragma unroll
            for (int j = 0; j < CHD; ++j) {
                float a = arow[j];
                float sg = (a > 0.f) ? 1.f : ((a < 0.f) ? -1.f : 0.f);
                float c = sg * fmaxf(fabsf(a) - thr[s][h], 0.f);
                comp[j] = c; m = fmaxf(m, c);
            }
            float sum = 0.f;
            #pragma unroll
            for (int j = 0; j < CHD; ++j) { comp[j] = expf(comp[j] - m); sum += comp[j]; }
            float wts2v = tw[s] / sum;
            #pragma unroll
            for (int j = 0; j < CHD; ++j) acc[j] += wts2v * comp[j];
        }
        for (int j = 0; j < CHD; ++j)
            sac[(h * CHD + i) * CHD + j] = acc[j];
    }
    __syncthreads();
    // W = proj @ attnc (head-block-diagonal): 36 outputs/thread x 12 fma
    float* Wb = Wm + (size_t)b * NC * NC;
    for (int idx = threadIdx.x; idx < NC * NC; idx += 256) {
        int m = idx / NC, col = idx % NC;
        int h = col / CHD, j = col % CHD;
        const float* pr = proj_w + m * NC + h * CHD;
        const float* ar = sac + h * CHD * CHD + j;
        float s = 0.f;
        #pragma unroll
        for (int i = 0; i < CHD; ++i) s += pr[i] * ar[i * CHD];
        Wb[idx] = s;
    }
}

// ---------------- launch ----------------
extern "C" void kernel_launch(void* const* d_in, const int* in_sizes, int n_in,
                              void* d_out, int out_size, void* d_ws, size_t ws_size,
                              hipStream_t stream) {
    const float* x       = (const float*)d_in[0];
    const float* norm1_w = (const float*)d_in[1];
    const float* norm1_b = (const float*)d_in[2];
    const float* qkv_w   = (const float*)d_in[3];
    const float* qkv_dw  = (const float*)d_in[4];
    const float* proj_w  = (const float*)d_in[5];
    const float* temp    = (const float*)d_in[6];
    const float* thw     = (const float*)d_in[7];
    const float* aw1     = (const float*)d_in[8];
    const float* ab1     = (const float*)d_in[9];
    const float* aw2     = (const float*)d_in[10];
    const float* ab2     = (const float*)d_in[11];
    const float* norm2_w = (const float*)d_in[12];
    const float* norm2_b = (const float*)d_in[13];
    const float* in_w    = (const float*)d_in[14];
    const float* main_w  = (const float*)d_in[15];
    const float* lp_w    = (const float*)d_in[16];
    const float* hp_w    = (const float*)d_in[17];
    const float* ld_w    = (const float*)d_in[18];
    const float* hd_w    = (const float*)d_in[19];
    const float* out_w   = (const float*)d_in[20];
    float* out = (float*)d_out;

    // ---- workspace layout ----
    char* ws = (char*)d_ws;
    float* x1    = (float*)(ws + 0);            // 12,582,912 fp32 residual stream
    u16*   qkv1  = (u16*)(ws + 18874368);       // 18,874,368 bf16 [2][288][NPIX]
    u16*   qkv2  = (u16*)(ws + 37748736);       // 18,874,368 bf16 [2][288][NPIX]
    float* scl   = (float*)(ws + 56623104);     // 1,536 B raw sum-of-squares
    float* attn  = (float*)(ws + 56624640);     // 9,216 B raw dots (scl+attn zeroed together)
    char*  F0    = ws + 56672256;
    // Wm (73,728 B): dead before cat(F0) is written; overlap is safe.
    float* Wm    = (float*)(ws + 56655872);
    const size_t S_full = 33423360;
    bool full = ws_size >= (size_t)56672256 + S_full;   // 90,095,616

    dim3 blk(256);
    // ---- attention half ----
    (void)hipMemsetAsync(scl, 0, 10752, stream);   // scl (1536B) + attn (9216B)
    gemm1x1_kernel<u16, false, 1, true><<<dim3(128, 3, NB), blk, 0, stream>>>(
        nullptr, qkv_w, nullptr, qkv1, 288, 96, 0, (size_t)288 * NPIX, 0,
        x, norm1_w, norm1_b);                      // LN1 fused into B staging
    dwconv3x3_kernel<false><<<dim3(2, NB * 288), blk, 0, stream>>>(
        qkv1, qkv_dw, qkv2, 288, 288, 1, scl);     // + fused qk sum-of-squares
    attn_kernel<<<dim3(4, NB * NHD * CHD), blk, 0, stream>>>(qkv2, attn);
    sts_kernel<<<dim3(NB), blk, 0, stream>>>(attn, scl, temp, thw, aw1, ab1, aw2, ab2,
                                             proj_w, Wm);
    // x1 = x + W @ v   (av+proj fused; v = qkv2 channels 192..287)
    gemm1x1_kernel<float, true, 0><<<dim3(128, 1, NB), blk, 0, stream>>>(
        qkv2 + (size_t)192 * NPIX, Wm, x, x1, 96, 96,
        (size_t)288 * NPIX, (size_t)NC * NPIX, (size_t)NC * NC,
        nullptr, nullptr, nullptr);
    // ---- FFN half ----
    if (full) {
        u16* yi  = qkv1;     // fp16, 33.4 MB spanning qkv1+qkv2 (dead now)
        u16* cat = (u16*)F0; // bf16
        gemm1x1_kernel<u16, false, 2, true><<<dim3(128, 4, NB), blk, 0, stream>>>(
            nullptr, in_w, nullptr, yi, H2C, 96, 0, (size_t)H2C * NPIX, 0,
            x1, norm2_w, norm2_b);                 // LN2 fused into B staging
        ffnstream_kernel<<<dim3(4, HIDC, NB), dim3(64), 0, stream>>>(
            yi, main_w, lp_w, hp_w, ld_w, hd_w, cat);
        gemm1x1_kernel<float, true, 0><<<dim3(128, 1, NB), blk, 0, stream>>>(
            cat, out_w, x1, out, 96, H2C, (size_t)H2C * NPIX, (size_t)NC * NPIX, 0,
            nullptr, nullptr, nullptr);
    } else {
        for (int b = 0; b < NB; ++b) {
            u16* yi  = qkv1;
            u16* cat = qkv2;
            gemm1x1_kernel<u16, false, 2, true><<<dim3(128, 4, 1), blk, 0, stream>>>(
                nullptr, in_w, nullptr, yi, H2C, 96, 0, 0, 0,
                x1 + (size_t)b * NC * NPIX, norm2_w, norm2_b);
            ffnstream_kernel<<<dim3(4, HIDC, 1), dim3(64), 0, stream>>>(
                yi, main_w, lp_w, hp_w, ld_w, hd_w, cat);
            gemm1x1_kernel<float, true, 0><<<dim3(128, 1, 1), blk, 0, stream>>>(
                cat, out_w, x1 + (size_t)b * NC * NPIX, out + (size_t)b * NC * NPIX,
                96, H2C, 0, 0, 0, nullptr, nullptr, nullptr);
        }
    }
}

// Round 13
// 353.494 us; speedup vs baseline: 1.0915x; 1.0915x over previous
//
#include <hip/hip_runtime.h>
#include <hip/hip_bf16.h>
#include <hip/hip_fp16.h>

// Problem constants
#define NB   2
#define NC   96
#define NW   128
#define NPIX 16384   // 128*128
#define NHD  8
#define CHD  12
#define HIDC 255
#define H2C  510
#define H4C  1020

typedef __hip_bfloat16 bf16;
typedef unsigned short u16;
typedef unsigned int   u32;
typedef __half2 h2t;

typedef __attribute__((ext_vector_type(8))) __bf16 bfrag;
typedef __attribute__((ext_vector_type(4))) float  ffrag;

__device__ __forceinline__ float bfu(u16 u)  { return __uint_as_float(((u32)u) << 16); }
__device__ __forceinline__ float bflo(u32 u) { return __uint_as_float(u << 16); }
__device__ __forceinline__ float bfhi(u32 u) { return __uint_as_float(u & 0xffff0000u); }
__device__ __forceinline__ u16 f2u16(float a) {
    bf16 x = __float2bfloat16(a); return *(u16*)&x;
}
__device__ __forceinline__ u32 packbf(float a, float b) {
    return (u32)f2u16(a) | ((u32)f2u16(b) << 16);
}
__device__ __forceinline__ uint4 pack8(const float o[8]) {
    uint4 r; r.x = packbf(o[0], o[1]); r.y = packbf(o[2], o[3]);
    r.z = packbf(o[4], o[5]); r.w = packbf(o[6], o[7]); return r;
}

// half2 bit helpers
__device__ __forceinline__ h2t H2u(u32 v) { return __builtin_bit_cast(h2t, v); }
__device__ __forceinline__ u32 U32h(h2t v) { return __builtin_bit_cast(u32, v); }
// packed fp16 relu: single v_pk_max_f16 (inline asm: fp16 __hmax2 overload is
// ambiguous/bf16-routed on ROCm 7.2 with both fp16+bf16 headers included).
__device__ __forceinline__ h2t relu2(h2t v) {
    u32 r, u = U32h(v);
    asm("v_pk_max_f16 %0, %1, 0" : "=v"(r) : "v"(u));
    return H2u(r);
}
// splat low/high half of a packed fp16 pair held in a VGPR u32.
__device__ __forceinline__ h2t wtap(const h2t* a, int idx) {
    u32 u = U32h(a[idx >> 1]);
    u32 r = (idx & 1) ? ((u & 0xFFFF0000u) | (u >> 16)) : ((u << 16) | (u & 0xFFFFu));
    return H2u(r);
}

// ================= streaming FFN midsection =================
// One wave = (group g of 4 channels, 32-row strip, batch). R8 config:
// strip 32, VGPR packed weights, depth-2 row prefetch, unroll 3. 86-93us.
// NO waves/EU bound (R5: (64,4) -> 64-VGPR clamp -> 1GB spill).
struct Trip { h2t L, C, R; };
__device__ __forceinline__ Trip shift3(h2t c2, bool repl, int lane) {
    u32 d = U32h(c2);
    u32 up = (u32)__shfl_up((int)d, 1);
    u32 dn = (u32)__shfl_down((int)d, 1);
    if (lane == 0)  up = repl ? (d << 16) : 0u;
    if (lane == 63) dn = repl ? (d >> 16) : 0u;
    Trip t; t.C = c2;
    t.L = H2u((up >> 16) | (d << 16));
    t.R = H2u((d >> 16) | (dn << 16));
    return t;
}
__device__ __forceinline__ h2t ldrow2(const u16* base, int row, int lane) {
    return ((unsigned)row < 128u) ? *(const h2t*)(base + row * NW + lane * 2) : H2u(0u);
}
#define CONV3(W, c, T, Pa, Pb, Pc)                                             \
    Pc = __hfma2(wtap(W, (c)*9+0), T.L, __hfma2(wtap(W, (c)*9+1), T.C,         \
         __hfma2(wtap(W, (c)*9+2), T.R, Pc)));                                 \
    Pb = __hfma2(wtap(W, (c)*9+3), T.L, __hfma2(wtap(W, (c)*9+4), T.C,         \
         __hfma2(wtap(W, (c)*9+5), T.R, Pb)));                                 \
    Pa = __hfma2(wtap(W, (c)*9+6), T.L, __hfma2(wtap(W, (c)*9+7), T.C,         \
         __hfma2(wtap(W, (c)*9+8), T.R, Pa)));

__global__ __launch_bounds__(64) void ffnstream_kernel(
    const u16* __restrict__ yi, const float* __restrict__ main_w,
    const float* __restrict__ lp_w, const float* __restrict__ hp_w,
    const float* __restrict__ ld_w, const float* __restrict__ hd_w,
    u16* __restrict__ cat) {
    const int lane = threadIdx.x;
    const int g = blockIdx.y;
    const int R0 = blockIdx.x * 32, R1 = R0 + 32;
    const int L0 = max(R0 - 2, 0), L1 = min(R1 + 1, 127);
    const int P0 = max(R0 - 1, 0), P1 = min(R1, 127);
    const u16* yib = yi + (size_t)blockIdx.z * H2C * NPIX;
    u16* catb = cat + (size_t)blockIdx.z * H2C * NPIX;
    const u16* s0p = yib + (size_t)(2 * g) * NPIX;
    const u16* s1p = yib + (size_t)(2 * g + 1) * NPIX;

    h2t wm[18], wl[18], wh[18], wd[18], we[18];
    {
        const float* pm = main_w + 36 * g;
        const float* pl = lp_w + 36 * g;
        const float* ph = hp_w + 36 * g;
        const float* pd = ld_w + 36 * g;
        const float* pe = hd_w + 36 * g;
        #pragma unroll
        for (int k = 0; k < 18; ++k) {
            wm[k] = __halves2half2(__float2half(pm[2*k]), __float2half(pm[2*k+1]));
            wl[k] = __halves2half2(__float2half(pl[2*k]), __float2half(pl[2*k+1]));
            wh[k] = __halves2half2(__float2half(ph[2*k]), __float2half(ph[2*k+1]));
            wd[k] = __halves2half2(__float2half(pd[2*k]), __float2half(pd[2*k+1]));
            we[k] = __halves2half2(__float2half(pe[2*k]), __float2half(pe[2*k+1]));
        }
    }
    const h2t z = H2u(0u);
    const __half k9h = __float2half(1.f / 9.f);
    const h2t k9 = __halves2half2(k9h, k9h);

    h2t ymP0[4], ymP1[4], ymP2[4];
    h2t ymRa[4], ymRb[4], ymRc[4];
    h2t lpP0[4], lpP1[4], lpP2[4];
    h2t hpP0[4], hpP1[4], hpP2[4];
    h2t cd0 = z, cd1 = z, cd2 = z;
    h2t ce0 = z, ce1 = z, ce2 = z;
    #pragma unroll
    for (int c = 0; c < 4; ++c) {
        ymP0[c] = ymP1[c] = ymP2[c] = z;
        ymRa[c] = ymRb[c] = ymRc[c] = z;
        lpP0[c] = lpP1[c] = lpP2[c] = z;
        hpP0[c] = hpP1[c] = hpP2[c] = z;
    }

    const int ys = max(R0 - 3, 0) - 1;
    const int ye = R1 + 3;
    h2t cur0 = ldrow2(s0p, ys, lane),     cur1 = ldrow2(s1p, ys, lane);
    h2t nx10 = ldrow2(s0p, ys + 1, lane), nx11 = ldrow2(s1p, ys + 1, lane);
    #pragma unroll 3
    for (int yy = ys; yy <= ye; ++yy) {
        h2t nx20 = ldrow2(s0p, yy + 2, lane), nx21 = ldrow2(s1p, yy + 2, lane);
        // A
        {
            Trip t0 = shift3(cur0, false, lane);
            Trip t1 = shift3(cur1, false, lane);
            CONV3(wm, 0, t0, ymP0[0], ymP1[0], ymP2[0]);
            CONV3(wm, 1, t0, ymP0[1], ymP1[1], ymP2[1]);
            CONV3(wm, 2, t1, ymP0[2], ymP1[2], ymP2[2]);
            CONV3(wm, 3, t1, ymP0[3], ymP1[3], ymP2[3]);
        }
        // B
        #pragma unroll
        for (int c = 0; c < 4; ++c) {
            h2t n = relu2(ymP0[c]);
            ymRc[c] = ymRb[c]; ymRb[c] = ymRa[c]; ymRa[c] = n;
            ymP0[c] = ymP1[c]; ymP1[c] = ymP2[c]; ymP2[c] = z;
        }
        // C
        int y_l = yy - 2;
        if (y_l >= L0 && y_l <= L1) {
            #pragma unroll
            for (int c = 0; c < 4; ++c) {
                h2t top = (y_l == 0)   ? ymRb[c] : ymRc[c];
                h2t bot = (y_l == 127) ? ymRb[c] : ymRa[c];
                h2t vs = __hadd2(__hadd2(top, ymRb[c]), bot);
                Trip tv = shift3(vs, true, lane);
                h2t l  = __hmul2(__hadd2(__hadd2(tv.L, tv.C), tv.R), k9);
                h2t hb = __hsub2(ymRb[c], l);
                Trip tl = shift3(l, false, lane);
                CONV3(wl, c, tl, lpP0[c], lpP1[c], lpP2[c]);
                Trip th = shift3(hb, false, lane);
                CONV3(wh, c, th, hpP0[c], hpP1[c], hpP2[c]);
            }
        }
        // E
        int y_p = yy - 3;
        {
            h2t lpN[4], hpN[4];
            #pragma unroll
            for (int c = 0; c < 4; ++c) {
                lpN[c] = relu2(lpP0[c]); hpN[c] = relu2(hpP0[c]);
                lpP0[c] = lpP1[c]; lpP1[c] = lpP2[c]; lpP2[c] = z;
                hpP0[c] = hpP1[c]; hpP1[c] = hpP2[c]; hpP2[c] = z;
            }
            if (y_p >= P0 && y_p <= P1) {
                #pragma unroll
                for (int c = 0; c < 4; ++c) {
                    bool low = (4 * g + c) < H2C;
                    h2t sld = low ? lpN[c] : hpN[c];
                    h2t shd = low ? hpN[c] : lpN[c];
                    Trip ts = shift3(sld, false, lane);
                    CONV3(wd, c, ts, cd0, cd1, cd2);
                    Trip tu = shift3(shd, false, lane);
                    CONV3(we, c, tu, ce0, ce1, ce2);
                }
            }
        }
        // F
        int y_c = yy - 4;
        if (y_c >= R0 && y_c < R1) {
            float a0 = fmaxf(__low2float(cd0), 0.f), a1 = fmaxf(__high2float(cd0), 0.f);
            float b0 = fmaxf(__low2float(ce0), 0.f), b1 = fmaxf(__high2float(ce0), 0.f);
            *(u32*)(catb + (size_t)g * NPIX + y_c * NW + lane * 2) = packbf(a0, a1);
            *(u32*)(catb + (size_t)(HIDC + g) * NPIX + y_c * NW + lane * 2) = packbf(b0, b1);
        }
        cd0 = cd1; cd1 = cd2; cd2 = z;
        ce0 = ce1; ce1 = ce2; ce2 = z;
        cur0 = nx10; cur1 = nx11;
        nx10 = nx20; nx11 = nx21;
    }
}

// ================= MFMA GEMM for 1x1 convs =================
// OFMT: 0 = f32 out, 1 = bf16 out, 2 = fp16 out
// MT (M-tile): 64 or 128. R12 lesson: MT=128 for M=96 gemms wastes 25% of
// the tile AND halves grid to 256 blocks (1/CU) -> staging bank conflicts
// un-hidden, 90us. MT=128 only where grid stays >=384 blocks (qkv, in_w);
// there it halves the L2/L3 B-panel re-read traffic.
// LNF: fuse channel-LayerNorm into B staging (fp32 xf -> per-pixel mu/inv
// over 96 channels -> bf16 once; identical rounding to separate ln kernel).
template <typename TOut, bool RES, int OFMT, bool LNF = false, int MT = 64>
__global__ __launch_bounds__(256) void gemm1x1_kernel(
    const u16* __restrict__ Bm, const float* __restrict__ Am,
    const float* __restrict__ res, TOut* __restrict__ Cm,
    int M, int K, size_t strideB, size_t strideC, size_t strideA,
    const float* __restrict__ xf, const float* __restrict__ lng,
    const float* __restrict__ lnb) {
    __shared__ u16 Ash[MT * 40];
    __shared__ u16 Bsh[128 * 40];
    __shared__ float lmu[128], linv[128];
    __shared__ float sred[2][128], qred[2][128];
    const u16* Bz = Bm + (size_t)blockIdx.z * strideB;
    const float* Az = Am + (size_t)blockIdx.z * strideA;
    const float* xz = LNF ? (xf + (size_t)blockIdx.z * NC * NPIX) : nullptr;
    int n0 = blockIdx.x * 128;
    int m0 = blockIdx.y * MT;
    int tid = threadIdx.x;
    int w = tid >> 6, l15 = tid & 15, q = (tid & 63) >> 4;
    int amm = tid >> 2, akc = (tid & 3) * 8;
    int bkk = tid >> 3, bs0 = tid & 7;

    if constexpr (LNF) {
        // per-pixel LN stats over the 96 channels of this 128-px tile
        int p = tid & 127, hh = tid >> 7;
        float s = 0.f, s2 = 0.f;
        #pragma unroll
        for (int c = 0; c < 48; ++c) {
            float v = xz[(size_t)(hh * 48 + c) * NPIX + n0 + p];
            s += v; s2 += v * v;
        }
        sred[hh][p] = s; qred[hh][p] = s2;
        __syncthreads();
        if (tid < 128) {
            float S = sred[0][tid] + sred[1][tid];
            float Q = qred[0][tid] + qred[1][tid];
            float m = S * (1.f / NC);
            float va = Q * (1.f / NC) - m * m;
            lmu[tid] = m; linv[tid] = rsqrtf(va + 1e-5f);
        }
        __syncthreads();
    }

    constexpr int NH = MT / 64;
    ffrag acc[NH][8];
    #pragma unroll
    for (int mt = 0; mt < NH; ++mt)
        #pragma unroll
        for (int nt = 0; nt < 8; ++nt)
            #pragma unroll
            for (int e = 0; e < 4; ++e) acc[mt][nt][e] = 0.f;

    for (int k0 = 0; k0 < K; k0 += 32) {
        // A staging: MT rows x 32 cols bf16
        #pragma unroll
        for (int half = 0; half < NH; ++half) {
            int gm = m0 + half * 64 + amm;
            float f[8];
            #pragma unroll
            for (int e = 0; e < 8; ++e) {
                int gk = k0 + akc + e;
                f[e] = (gm < M && gk < K) ? Az[(size_t)gm * K + gk] : 0.f;
            }
            u32* dst = (u32*)&Ash[(half * 64 + amm) * 40 + akc];
            #pragma unroll
            for (int e = 0; e < 4; ++e) dst[e] = packbf(f[2 * e], f[2 * e + 1]);
        }
        if constexpr (LNF) {
            int gk = k0 + bkk;           // K == 96 exactly, always in range
            const float* src = xz + (size_t)gk * NPIX + n0;
            float gc = lng[gk], bc = lnb[gk];
            #pragma unroll
            for (int pass = 0; pass < 2; ++pass) {
                int nn = (bs0 + pass * 8) * 8;
                float4 f0 = *(const float4*)(src + nn);
                float4 f1 = *(const float4*)(src + nn + 4);
                float f[8] = {f0.x, f0.y, f0.z, f0.w, f1.x, f1.y, f1.z, f1.w};
                #pragma unroll
                for (int e = 0; e < 8; ++e) {
                    float nv = (f[e] - lmu[nn + e]) * linv[nn + e] * gc + bc;
                    Bsh[(nn + e) * 40 + bkk] = f2u16(nv);
                }
            }
        } else {
            int gk = k0 + bkk;
            bool ok = gk < K;
            const u16* src = Bz + (size_t)gk * NPIX + n0;
            #pragma unroll
            for (int pass = 0; pass < 2; ++pass) {
                int nn = (bs0 + pass * 8) * 8;
                if (ok) {
                    uint4 v = *(const uint4*)(src + nn);
                    Bsh[(nn + 0) * 40 + bkk] = (u16)(v.x & 0xffff);
                    Bsh[(nn + 1) * 40 + bkk] = (u16)(v.x >> 16);
                    Bsh[(nn + 2) * 40 + bkk] = (u16)(v.y & 0xffff);
                    Bsh[(nn + 3) * 40 + bkk] = (u16)(v.y >> 16);
                    Bsh[(nn + 4) * 40 + bkk] = (u16)(v.z & 0xffff);
                    Bsh[(nn + 5) * 40 + bkk] = (u16)(v.z >> 16);
                    Bsh[(nn + 6) * 40 + bkk] = (u16)(v.w & 0xffff);
                    Bsh[(nn + 7) * 40 + bkk] = (u16)(v.w >> 16);
                } else {
                    #pragma unroll
                    for (int e = 0; e < 8; ++e) Bsh[(nn + e) * 40 + bkk] = 0;
                }
            }
        }
        __syncthreads();
        bfrag af[NH];
        #pragma unroll
        for (int half = 0; half < NH; ++half)
            af[half] = *(const bfrag*)&Ash[(half * 64 + w * 16 + l15) * 40 + q * 8];
        #pragma unroll
        for (int nt = 0; nt < 8; ++nt) {
            bfrag bf = *(const bfrag*)&Bsh[(nt * 16 + l15) * 40 + q * 8];
            #pragma unroll
            for (int half = 0; half < NH; ++half)
                acc[half][nt] = __builtin_amdgcn_mfma_f32_16x16x32_bf16(af[half], bf, acc[half][nt], 0, 0, 0);
        }
        __syncthreads();
    }
    TOut* Cz = Cm + (size_t)blockIdx.z * strideC;
    const float* rz = res + (RES ? (size_t)blockIdx.z * strideC : 0);
    #pragma unroll
    for (int mt = 0; mt < NH; ++mt) {
        int mrow = m0 + mt * 64 + w * 16 + q * 4;
        #pragma unroll
        for (int nt = 0; nt < 8; ++nt) {
            int col = n0 + nt * 16 + l15;
            #pragma unroll
            for (int r = 0; r < 4; ++r) {
                int row = mrow + r;
                if (row < M) {
                    float v = acc[mt][nt][r];
                    if (RES) v += rz[(size_t)row * NPIX + col];
                    if constexpr (OFMT == 0) {
                        ((float*)Cz)[(size_t)row * NPIX + col] = v;
                    } else if constexpr (OFMT == 1) {
                        ((u16*)Cz)[(size_t)row * NPIX + col] = f2u16(v);
                    } else {
                        __half hh = __float2half(v);
                        ((u16*)Cz)[(size_t)row * NPIX + col] = __builtin_bit_cast(u16, hh);
                    }
                }
            }
        }
    }
}

// load a 1x10 window row (8 aligned + 2 halo) with zero padding (global memory)
__device__ __forceinline__ void load_row_zpad(const u16* ib, int iy, int x0, float a[10]) {
    if (iy < 0 || iy >= NW) {
        #pragma unroll
        for (int k = 0; k < 10; ++k) a[k] = 0.f;
        return;
    }
    const u16* rp = ib + iy * NW;
    uint4 v = *(const uint4*)(rp + x0);
    a[1]=bflo(v.x); a[2]=bfhi(v.x); a[3]=bflo(v.y); a[4]=bfhi(v.y);
    a[5]=bflo(v.z); a[6]=bfhi(v.z); a[7]=bflo(v.w); a[8]=bfhi(v.w);
    a[0] = (x0 > 0)   ? bfu(rp[x0 - 1]) : 0.f;
    a[9] = (x0 < 120) ? bfu(rp[x0 + 8]) : 0.f;
}

// ---------------- depthwise 3x3 (qkv), zero pad, 4 rows x 8 px/thread -------
// Fused qknorm: channels < 192 (q,k) accumulate sum-of-squares of the conv
// output (pre-bf16-rounding, sub-ulp diff) into sqsum[b*192+oc] via one
// atomicAdd per block (2 blocks/channel).
template <bool RELU>
__global__ __launch_bounds__(256) void dwconv3x3_kernel(
    const u16* __restrict__ in, const float* __restrict__ w,
    u16* __restrict__ out, int CHN, int ICN, int idiv,
    float* __restrict__ sqsum) {
    int id = blockIdx.x * 256 + threadIdx.x;   // 0..511
    int ty = id >> 4, tx = id & 15;
    int y0 = ty * 4, x0 = tx * 8;
    int b = blockIdx.y / CHN, oc = blockIdx.y % CHN;
    int ic = oc / idiv;
    const u16* ib = in + ((size_t)b * ICN + ic) * NPIX;
    float a[6][10];
    #pragma unroll
    for (int k = 0; k < 6; ++k) load_row_zpad(ib, y0 - 1 + k, x0, a[k]);
    const float* wr = w + (size_t)oc * 9;
    float w9[9];
    #pragma unroll
    for (int k = 0; k < 9; ++k) w9[k] = wr[k];
    u16* ob = out + ((size_t)b * CHN + oc) * NPIX + y0 * NW + x0;
    float s2 = 0.f;
    #pragma unroll
    for (int jr = 0; jr < 4; ++jr) {
        float o[8];
        #pragma unroll
        for (int j = 0; j < 8; ++j) {
            float s = 0.f;
            #pragma unroll
            for (int r = 0; r < 3; ++r)
                #pragma unroll
                for (int kx = 0; kx < 3; ++kx)
                    s += w9[r * 3 + kx] * a[jr + r][j + kx];
            o[j] = RELU ? fmaxf(s, 0.f) : s;
            s2 += o[j] * o[j];
        }
        *(uint4*)(ob + jr * NW) = pack8(o);
    }
    if (oc < 192) {   // block-uniform branch
        #pragma unroll
        for (int off = 32; off > 0; off >>= 1) s2 += __shfl_down(s2, off, 64);
        __shared__ float prt[4];
        int wid = threadIdx.x >> 6;
        if ((threadIdx.x & 63) == 0) prt[wid] = s2;
        __syncthreads();
        if (threadIdx.x == 0)
            atomicAdd(&sqsum[b * 192 + oc], prt[0] + prt[1] + prt[2] + prt[3]);
    }
}

// ---------------- raw attn dots, 4-way pixel split + atomicAdd ----------------
__global__ __launch_bounds__(256) void attn_kernel(
    const u16* __restrict__ qkv2, float* __restrict__ attn_raw) {
    int blk = blockIdx.y;  // ((b*NHD+h)*CHD+i)
    int slice = blockIdx.x;
    int i = blk % CHD; int h = (blk / CHD) % NHD; int b = blk / (CHD * NHD);
    const u16* q = qkv2 + ((size_t)b * 288 + h * CHD + i) * NPIX;
    const u16* k = qkv2 + ((size_t)b * 288 + 96 + h * CHD) * NPIX;
    float acc[CHD];
    #pragma unroll
    for (int j = 0; j < CHD; ++j) acc[j] = 0.f;
    int p0 = slice * 4096;
    #pragma unroll
    for (int it = 0; it < 2; ++it) {
        int p = p0 + it * 2048 + threadIdx.x * 8;
        uint4 qv = *(const uint4*)(q + p);
        float qf[8];
        qf[0]=bflo(qv.x); qf[1]=bfhi(qv.x); qf[2]=bflo(qv.y); qf[3]=bfhi(qv.y);
        qf[4]=bflo(qv.z); qf[5]=bfhi(qv.z); qf[6]=bflo(qv.w); qf[7]=bfhi(qv.w);
        #pragma unroll
        for (int j = 0; j < CHD; ++j) {
            uint4 kv = *(const uint4*)(k + (size_t)j * NPIX + p);
            float s = qf[0]*bflo(kv.x) + qf[1]*bfhi(kv.x) + qf[2]*bflo(kv.y) + qf[3]*bfhi(kv.y)
                    + qf[4]*bflo(kv.z) + qf[5]*bfhi(kv.z) + qf[6]*bflo(kv.w) + qf[7]*bfhi(kv.w);
            acc[j] += s;
        }
    }
    __shared__ float part[4][CHD];
    int wid = threadIdx.x >> 6, lane = threadIdx.x & 63;
    #pragma unroll
    for (int j = 0; j < CHD; ++j) {
        float v = acc[j];
        #pragma unroll
        for (int off = 32; off > 0; off >>= 1) v += __shfl_down(v, off, 64);
        if (lane == 0) part[wid][j] = v;
    }
    __syncthreads();
    if (threadIdx.x < CHD) {
        int j = threadIdx.x;
        float d = part[0][j] + part[1][j] + part[2][j] + part[3][j];
        atomicAdd(&attn_raw[(size_t)blk * CHD + j], d);
    }
}

// ---------------- STS + W-mix fused ----------------
// sclr holds raw per-channel sum-of-squares (from dwconv); convert to
// reciprocal norms in LDS, scale raw dots, thresholds, 4-way softmax mix
// -> attnc (LDS only), then W = proj @ attnc (av+proj fusion).
__global__ __launch_bounds__(256) void sts_kernel(
    const float* __restrict__ attn, const float* __restrict__ sclr,
    const float* __restrict__ temp, const float* __restrict__ tw,
    const float* __restrict__ w1, const float* __restrict__ b1,
    const float* __restrict__ w2, const float* __restrict__ b2,
    const float* __restrict__ proj_w, float* __restrict__ Wm) {
    int b = blockIdx.x;
    __shared__ float sat[NHD * CHD * CHD];
    __shared__ float sac[NHD * CHD * CHD];
    __shared__ float srs[192];
    __shared__ float pavg[NHD * CHD];
    __shared__ float avg[NHD];
    __shared__ float thr[4][NHD];
    if (threadIdx.x < 192) {
        float r = sclr[b * 192 + threadIdx.x];
        srs[threadIdx.x] = 1.f / fmaxf(sqrtf(r), 1e-12f);
    }
    __syncthreads();
    for (int idx = threadIdx.x; idx < NHD * CHD * CHD; idx += 256) {
        int h = idx / (CHD * CHD); int r = idx % (CHD * CHD);
        int i = r / CHD, j = r % CHD;
        sat[idx] = attn[(size_t)b * NHD * CHD * CHD + idx]
                 * srs[h * CHD + i] * srs[96 + h * CHD + j] * temp[h];
    }
    __syncthreads();
    if (threadIdx.x < NHD * CHD) {
        float s = 0.f;
        const float* row = sat + threadIdx.x * CHD;
        #pragma unroll
        for (int j = 0; j < CHD; ++j) s += fabsf(row[j]);
        pavg[threadIdx.x] = s;
    }
    __syncthreads();
    if (threadIdx.x < NHD) {
        float s = 0.f;
        #pragma unroll
        for (int i = 0; i < CHD; ++i) s += pavg[threadIdx.x * CHD + i];
        avg[threadIdx.x] = s * (1.f / (CHD * CHD));
    }
    __syncthreads();
    if (threadIdx.x < 4) {
        int s = threadIdx.x;
        float t1[NHD];
        for (int hp = 0; hp < NHD; ++hp) {
            float u = b1[s * NHD + hp];
            for (int h = 0; h < NHD; ++h) u += avg[h] * w1[s * 64 + hp * NHD + h];
            t1[hp] = fmaxf(u, 0.f);
        }
        for (int hp = 0; hp < NHD; ++hp) {
            float u = b2[s * NHD + hp];
            for (int h = 0; h < NHD; ++h) u += t1[h] * w2[s * 64 + hp * NHD + h];
            float gg = 1.f / (1.f + expf(-u));
            thr[s][hp] = avg[hp] * gg;
        }
    }
    __syncthreads();
    if (threadIdx.x < NHD * CHD) {
        int h = threadIdx.x / CHD, i = threadIdx.x % CHD;
        const float* arow = sat + (h * CHD + i) * CHD;
        float acc[CHD];
        #pragma unroll
        for (int j = 0; j < CHD; ++j) acc[j] = 0.f;
        for (int s = 0; s < 4; ++s) {
            float comp[CHD]; float m = -1e30f;
            #pragma unroll
            for (int j = 0; j < CHD; ++j) {
                float a = arow[j];
                float sg = (a > 0.f) ? 1.f : ((a < 0.f) ? -1.f : 0.f);
                float c = sg * fmaxf(fabsf(a) - thr[s][h], 0.f);
                comp[j] = c; m = fmaxf(m, c);
            }
            float sum = 0.f;
            #pragma unroll
            for (int j = 0; j < CHD; ++j) { comp[j] = expf(comp[j] - m); sum += comp[j]; }
            float wts2v = tw[s] / sum;
            #pragma unroll
            for (int j = 0; j < CHD; ++j) acc[j] += wts2v * comp[j];
        }
        for (int j = 0; j < CHD; ++j)
            sac[(h * CHD + i) * CHD + j] = acc[j];
    }
    __syncthreads();
    // W = proj @ attnc (head-block-diagonal): 36 outputs/thread x 12 fma
    float* Wb = Wm + (size_t)b * NC * NC;
    for (int idx = threadIdx.x; idx < NC * NC; idx += 256) {
        int m = idx / NC, col = idx % NC;
        int h = col / CHD, j = col % CHD;
        const float* pr = proj_w + m * NC + h * CHD;
        const float* ar = sac + h * CHD * CHD + j;
        float s = 0.f;
        #pragma unroll
        for (int i = 0; i < CHD; ++i) s += pr[i] * ar[i * CHD];
        Wb[idx] = s;
    }
}

// ---------------- launch ----------------
extern "C" void kernel_launch(void* const* d_in, const int* in_sizes, int n_in,
                              void* d_out, int out_size, void* d_ws, size_t ws_size,
                              hipStream_t stream) {
    const float* x       = (const float*)d_in[0];
    const float* norm1_w = (const float*)d_in[1];
    const float* norm1_b = (const float*)d_in[2];
    const float* qkv_w   = (const float*)d_in[3];
    const float* qkv_dw  = (const float*)d_in[4];
    const float* proj_w  = (const float*)d_in[5];
    const float* temp    = (const float*)d_in[6];
    const float* thw     = (const float*)d_in[7];
    const float* aw1     = (const float*)d_in[8];
    const float* ab1     = (const float*)d_in[9];
    const float* aw2     = (const float*)d_in[10];
    const float* ab2     = (const float*)d_in[11];
    const float* norm2_w = (const float*)d_in[12];
    const float* norm2_b = (const float*)d_in[13];
    const float* in_w    = (const float*)d_in[14];
    const float* main_w  = (const float*)d_in[15];
    const float* lp_w    = (const float*)d_in[16];
    const float* hp_w    = (const float*)d_in[17];
    const float* ld_w    = (const float*)d_in[18];
    const float* hd_w    = (const float*)d_in[19];
    const float* out_w   = (const float*)d_in[20];
    float* out = (float*)d_out;

    // ---- workspace layout ----
    char* ws = (char*)d_ws;
    float* x1    = (float*)(ws + 0);            // 12,582,912 fp32 residual stream
    u16*   qkv1  = (u16*)(ws + 18874368);       // 18,874,368 bf16 [2][288][NPIX]
    u16*   qkv2  = (u16*)(ws + 37748736);       // 18,874,368 bf16 [2][288][NPIX]
    float* scl   = (float*)(ws + 56623104);     // 1,536 B raw sum-of-squares
    float* attn  = (float*)(ws + 56624640);     // 9,216 B raw dots (scl+attn zeroed together)
    char*  F0    = ws + 56672256;
    // Wm (73,728 B): dead before cat(F0) is written; overlap is safe.
    float* Wm    = (float*)(ws + 56655872);
    const size_t S_full = 33423360;
    bool full = ws_size >= (size_t)56672256 + S_full;   // 90,095,616

    dim3 blk(256);
    // ---- attention half ----
    (void)hipMemsetAsync(scl, 0, 10752, stream);   // scl (1536B) + attn (9216B)
    gemm1x1_kernel<u16, false, 1, true, 128><<<dim3(128, 3, NB), blk, 0, stream>>>(
        nullptr, qkv_w, nullptr, qkv1, 288, 96, 0, (size_t)288 * NPIX, 0,
        x, norm1_w, norm1_b);                      // LN1 fused into B staging
    dwconv3x3_kernel<false><<<dim3(2, NB * 288), blk, 0, stream>>>(
        qkv1, qkv_dw, qkv2, 288, 288, 1, scl);     // + fused qk sum-of-squares
    attn_kernel<<<dim3(4, NB * NHD * CHD), blk, 0, stream>>>(qkv2, attn);
    sts_kernel<<<dim3(NB), blk, 0, stream>>>(attn, scl, temp, thw, aw1, ab1, aw2, ab2,
                                             proj_w, Wm);
    // x1 = x + W @ v   (av+proj fused; v = qkv2 channels 192..287)
    gemm1x1_kernel<float, true, 0, false, 64><<<dim3(128, 2, NB), blk, 0, stream>>>(
        qkv2 + (size_t)192 * NPIX, Wm, x, x1, 96, 96,
        (size_t)288 * NPIX, (size_t)NC * NPIX, (size_t)NC * NC,
        nullptr, nullptr, nullptr);
    // ---- FFN half ----
    if (full) {
        u16* yi  = qkv1;     // fp16, 33.4 MB spanning qkv1+qkv2 (dead now)
        u16* cat = (u16*)F0; // bf16
        gemm1x1_kernel<u16, false, 2, true, 128><<<dim3(128, 4, NB), blk, 0, stream>>>(
            nullptr, in_w, nullptr, yi, H2C, 96, 0, (size_t)H2C * NPIX, 0,
            x1, norm2_w, norm2_b);                 // LN2 fused into B staging
        ffnstream_kernel<<<dim3(4, HIDC, NB), dim3(64), 0, stream>>>(
            yi, main_w, lp_w, hp_w, ld_w, hd_w, cat);
        gemm1x1_kernel<float, true, 0, false, 64><<<dim3(128, 2, NB), blk, 0, stream>>>(
            cat, out_w, x1, out, 96, H2C, (size_t)H2C * NPIX, (size_t)NC * NPIX, 0,
            nullptr, nullptr, nullptr);
    } else {
        for (int b = 0; b < NB; ++b) {
            u16* yi  = qkv1;
            u16* cat = qkv2;
            gemm1x1_kernel<u16, false, 2, true, 128><<<dim3(128, 4, 1), blk, 0, stream>>>(
                nullptr, in_w, nullptr, yi, H2C, 96, 0, 0, 0,
                x1 + (size_t)b * NC * NPIX, norm2_w, norm2_b);
            ffnstream_kernel<<<dim3(4, HIDC, 1), dim3(64), 0, stream>>>(
                yi, main_w, lp_w, hp_w, ld_w, hd_w, cat);
            gemm1x1_kernel<float, true, 0, false, 64><<<dim3(128, 2, 1), blk, 0, stream>>>(
                cat, out_w, x1 + (size_t)b * NC * NPIX, out + (size_t)b * NC * NPIX,
                96, H2C, 0, 0, 0, nullptr, nullptr, nullptr);
        }
    }
}

// Round 14
// 349.267 us; speedup vs baseline: 1.1047x; 1.0121x over previous
//
#include <hip/hip_runtime.h>
#include <hip/hip_bf16.h>
#include <hip/hip_fp16.h>

// Problem constants
#define NB   2
#define NC   96
#define NW   128
#define NPIX 16384   // 128*128
#define NHD  8
#define CHD  12
#define HIDC 255
#define H2C  510
#define H4C  1020

typedef __hip_bfloat16 bf16;
typedef unsigned short u16;
typedef unsigned int   u32;
typedef __half2 h2t;

typedef __attribute__((ext_vector_type(8))) __bf16 bfrag;
typedef __attribute__((ext_vector_type(4))) float  ffrag;

__device__ __forceinline__ float bfu(u16 u)  { return __uint_as_float(((u32)u) << 16); }
__device__ __forceinline__ float bflo(u32 u) { return __uint_as_float(u << 16); }
__device__ __forceinline__ float bfhi(u32 u) { return __uint_as_float(u & 0xffff0000u); }
__device__ __forceinline__ u16 f2u16(float a) {
    bf16 x = __float2bfloat16(a); return *(u16*)&x;
}
__device__ __forceinline__ u32 packbf(float a, float b) {
    return (u32)f2u16(a) | ((u32)f2u16(b) << 16);
}
__device__ __forceinline__ uint4 pack8(const float o[8]) {
    uint4 r; r.x = packbf(o[0], o[1]); r.y = packbf(o[2], o[3]);
    r.z = packbf(o[4], o[5]); r.w = packbf(o[6], o[7]); return r;
}

// half2 bit helpers
__device__ __forceinline__ h2t H2u(u32 v) { return __builtin_bit_cast(h2t, v); }
__device__ __forceinline__ u32 U32h(h2t v) { return __builtin_bit_cast(u32, v); }
// packed fp16 relu: single v_pk_max_f16 (inline asm: fp16 __hmax2 overload is
// ambiguous/bf16-routed on ROCm 7.2 with both fp16+bf16 headers included).
__device__ __forceinline__ h2t relu2(h2t v) {
    u32 r, u = U32h(v);
    asm("v_pk_max_f16 %0, %1, 0" : "=v"(r) : "v"(u));
    return H2u(r);
}
// splat low/high half of a packed fp16 pair held in a VGPR u32.
__device__ __forceinline__ h2t wtap(const h2t* a, int idx) {
    u32 u = U32h(a[idx >> 1]);
    u32 r = (idx & 1) ? ((u & 0xFFFF0000u) | (u >> 16)) : ((u << 16) | (u & 0xFFFFu));
    return H2u(r);
}

// ================= streaming FFN midsection =================
// One wave = (group g of 4 channels, 32-row strip, batch). R8 config:
// strip 32, VGPR packed weights, depth-2 row prefetch, unroll 3. 86-93us.
// NO waves/EU bound (R5: (64,4) -> 64-VGPR clamp -> 1GB spill).
struct Trip { h2t L, C, R; };
__device__ __forceinline__ Trip shift3(h2t c2, bool repl, int lane) {
    u32 d = U32h(c2);
    u32 up = (u32)__shfl_up((int)d, 1);
    u32 dn = (u32)__shfl_down((int)d, 1);
    if (lane == 0)  up = repl ? (d << 16) : 0u;
    if (lane == 63) dn = repl ? (d >> 16) : 0u;
    Trip t; t.C = c2;
    t.L = H2u((up >> 16) | (d << 16));
    t.R = H2u((d >> 16) | (dn << 16));
    return t;
}
__device__ __forceinline__ h2t ldrow2(const u16* base, int row, int lane) {
    return ((unsigned)row < 128u) ? *(const h2t*)(base + row * NW + lane * 2) : H2u(0u);
}
#define CONV3(W, c, T, Pa, Pb, Pc)                                             \
    Pc = __hfma2(wtap(W, (c)*9+0), T.L, __hfma2(wtap(W, (c)*9+1), T.C,         \
         __hfma2(wtap(W, (c)*9+2), T.R, Pc)));                                 \
    Pb = __hfma2(wtap(W, (c)*9+3), T.L, __hfma2(wtap(W, (c)*9+4), T.C,         \
         __hfma2(wtap(W, (c)*9+5), T.R, Pb)));                                 \
    Pa = __hfma2(wtap(W, (c)*9+6), T.L, __hfma2(wtap(W, (c)*9+7), T.C,         \
         __hfma2(wtap(W, (c)*9+8), T.R, Pa)));

__global__ __launch_bounds__(64) void ffnstream_kernel(
    const u16* __restrict__ yi, const float* __restrict__ main_w,
    const float* __restrict__ lp_w, const float* __restrict__ hp_w,
    const float* __restrict__ ld_w, const float* __restrict__ hd_w,
    u16* __restrict__ cat) {
    const int lane = threadIdx.x;
    const int g = blockIdx.y;
    const int R0 = blockIdx.x * 32, R1 = R0 + 32;
    const int L0 = max(R0 - 2, 0), L1 = min(R1 + 1, 127);
    const int P0 = max(R0 - 1, 0), P1 = min(R1, 127);
    const u16* yib = yi + (size_t)blockIdx.z * H2C * NPIX;
    u16* catb = cat + (size_t)blockIdx.z * H2C * NPIX;
    const u16* s0p = yib + (size_t)(2 * g) * NPIX;
    const u16* s1p = yib + (size_t)(2 * g + 1) * NPIX;

    h2t wm[18], wl[18], wh[18], wd[18], we[18];
    {
        const float* pm = main_w + 36 * g;
        const float* pl = lp_w + 36 * g;
        const float* ph = hp_w + 36 * g;
        const float* pd = ld_w + 36 * g;
        const float* pe = hd_w + 36 * g;
        #pragma unroll
        for (int k = 0; k < 18; ++k) {
            wm[k] = __halves2half2(__float2half(pm[2*k]), __float2half(pm[2*k+1]));
            wl[k] = __halves2half2(__float2half(pl[2*k]), __float2half(pl[2*k+1]));
            wh[k] = __halves2half2(__float2half(ph[2*k]), __float2half(ph[2*k+1]));
            wd[k] = __halves2half2(__float2half(pd[2*k]), __float2half(pd[2*k+1]));
            we[k] = __halves2half2(__float2half(pe[2*k]), __float2half(pe[2*k+1]));
        }
    }
    const h2t z = H2u(0u);
    const __half k9h = __float2half(1.f / 9.f);
    const h2t k9 = __halves2half2(k9h, k9h);

    h2t ymP0[4], ymP1[4], ymP2[4];
    h2t ymRa[4], ymRb[4], ymRc[4];
    h2t lpP0[4], lpP1[4], lpP2[4];
    h2t hpP0[4], hpP1[4], hpP2[4];
    h2t cd0 = z, cd1 = z, cd2 = z;
    h2t ce0 = z, ce1 = z, ce2 = z;
    #pragma unroll
    for (int c = 0; c < 4; ++c) {
        ymP0[c] = ymP1[c] = ymP2[c] = z;
        ymRa[c] = ymRb[c] = ymRc[c] = z;
        lpP0[c] = lpP1[c] = lpP2[c] = z;
        hpP0[c] = hpP1[c] = hpP2[c] = z;
    }

    const int ys = max(R0 - 3, 0) - 1;
    const int ye = R1 + 3;
    h2t cur0 = ldrow2(s0p, ys, lane),     cur1 = ldrow2(s1p, ys, lane);
    h2t nx10 = ldrow2(s0p, ys + 1, lane), nx11 = ldrow2(s1p, ys + 1, lane);
    #pragma unroll 3
    for (int yy = ys; yy <= ye; ++yy) {
        h2t nx20 = ldrow2(s0p, yy + 2, lane), nx21 = ldrow2(s1p, yy + 2, lane);
        // A
        {
            Trip t0 = shift3(cur0, false, lane);
            Trip t1 = shift3(cur1, false, lane);
            CONV3(wm, 0, t0, ymP0[0], ymP1[0], ymP2[0]);
            CONV3(wm, 1, t0, ymP0[1], ymP1[1], ymP2[1]);
            CONV3(wm, 2, t1, ymP0[2], ymP1[2], ymP2[2]);
            CONV3(wm, 3, t1, ymP0[3], ymP1[3], ymP2[3]);
        }
        // B
        #pragma unroll
        for (int c = 0; c < 4; ++c) {
            h2t n = relu2(ymP0[c]);
            ymRc[c] = ymRb[c]; ymRb[c] = ymRa[c]; ymRa[c] = n;
            ymP0[c] = ymP1[c]; ymP1[c] = ymP2[c]; ymP2[c] = z;
        }
        // C
        int y_l = yy - 2;
        if (y_l >= L0 && y_l <= L1) {
            #pragma unroll
            for (int c = 0; c < 4; ++c) {
                h2t top = (y_l == 0)   ? ymRb[c] : ymRc[c];
                h2t bot = (y_l == 127) ? ymRb[c] : ymRa[c];
                h2t vs = __hadd2(__hadd2(top, ymRb[c]), bot);
                Trip tv = shift3(vs, true, lane);
                h2t l  = __hmul2(__hadd2(__hadd2(tv.L, tv.C), tv.R), k9);
                h2t hb = __hsub2(ymRb[c], l);
                Trip tl = shift3(l, false, lane);
                CONV3(wl, c, tl, lpP0[c], lpP1[c], lpP2[c]);
                Trip th = shift3(hb, false, lane);
                CONV3(wh, c, th, hpP0[c], hpP1[c], hpP2[c]);
            }
        }
        // E
        int y_p = yy - 3;
        {
            h2t lpN[4], hpN[4];
            #pragma unroll
            for (int c = 0; c < 4; ++c) {
                lpN[c] = relu2(lpP0[c]); hpN[c] = relu2(hpP0[c]);
                lpP0[c] = lpP1[c]; lpP1[c] = lpP2[c]; lpP2[c] = z;
                hpP0[c] = hpP1[c]; hpP1[c] = hpP2[c]; hpP2[c] = z;
            }
            if (y_p >= P0 && y_p <= P1) {
                #pragma unroll
                for (int c = 0; c < 4; ++c) {
                    bool low = (4 * g + c) < H2C;
                    h2t sld = low ? lpN[c] : hpN[c];
                    h2t shd = low ? hpN[c] : lpN[c];
                    Trip ts = shift3(sld, false, lane);
                    CONV3(wd, c, ts, cd0, cd1, cd2);
                    Trip tu = shift3(shd, false, lane);
                    CONV3(we, c, tu, ce0, ce1, ce2);
                }
            }
        }
        // F
        int y_c = yy - 4;
        if (y_c >= R0 && y_c < R1) {
            float a0 = fmaxf(__low2float(cd0), 0.f), a1 = fmaxf(__high2float(cd0), 0.f);
            float b0 = fmaxf(__low2float(ce0), 0.f), b1 = fmaxf(__high2float(ce0), 0.f);
            *(u32*)(catb + (size_t)g * NPIX + y_c * NW + lane * 2) = packbf(a0, a1);
            *(u32*)(catb + (size_t)(HIDC + g) * NPIX + y_c * NW + lane * 2) = packbf(b0, b1);
        }
        cd0 = cd1; cd1 = cd2; cd2 = z;
        ce0 = ce1; ce1 = ce2; ce2 = z;
        cur0 = nx10; cur1 = nx11;
        nx10 = nx20; nx11 = nx21;
    }
}

// ================= MFMA GEMM for 1x1 convs =================
// OFMT: 0 = f32 out, 1 = bf16 out, 2 = fp16 out
// MT (M-tile): 64 or 128. R12 lesson: MT=128 for M=96 gemms wastes 25% of
// the tile AND halves grid to 256 blocks (1/CU) -> staging bank conflicts
// un-hidden, 90us. MT=128 only where grid stays >=384 blocks (qkv, in_w).
// LNF: fuse channel-LayerNorm into B staging (fp32 xf -> per-pixel mu/inv
// over 96 channels -> bf16 once; identical rounding to separate ln kernel).
template <typename TOut, bool RES, int OFMT, bool LNF = false, int MT = 64>
__global__ __launch_bounds__(256) void gemm1x1_kernel(
    const u16* __restrict__ Bm, const float* __restrict__ Am,
    const float* __restrict__ res, TOut* __restrict__ Cm,
    int M, int K, size_t strideB, size_t strideC, size_t strideA,
    const float* __restrict__ xf, const float* __restrict__ lng,
    const float* __restrict__ lnb) {
    __shared__ u16 Ash[MT * 40];
    __shared__ u16 Bsh[128 * 40];
    __shared__ float lmu[128], linv[128];
    __shared__ float sred[2][128], qred[2][128];
    const u16* Bz = Bm + (size_t)blockIdx.z * strideB;
    const float* Az = Am + (size_t)blockIdx.z * strideA;
    const float* xz = LNF ? (xf + (size_t)blockIdx.z * NC * NPIX) : nullptr;
    int n0 = blockIdx.x * 128;
    int m0 = blockIdx.y * MT;
    int tid = threadIdx.x;
    int w = tid >> 6, l15 = tid & 15, q = (tid & 63) >> 4;
    int amm = tid >> 2, akc = (tid & 3) * 8;
    int bkk = tid >> 3, bs0 = tid & 7;

    if constexpr (LNF) {
        // per-pixel LN stats over the 96 channels of this 128-px tile
        int p = tid & 127, hh = tid >> 7;
        float s = 0.f, s2 = 0.f;
        #pragma unroll
        for (int c = 0; c < 48; ++c) {
            float v = xz[(size_t)(hh * 48 + c) * NPIX + n0 + p];
            s += v; s2 += v * v;
        }
        sred[hh][p] = s; qred[hh][p] = s2;
        __syncthreads();
        if (tid < 128) {
            float S = sred[0][tid] + sred[1][tid];
            float Q = qred[0][tid] + qred[1][tid];
            float m = S * (1.f / NC);
            float va = Q * (1.f / NC) - m * m;
            lmu[tid] = m; linv[tid] = rsqrtf(va + 1e-5f);
        }
        __syncthreads();
    }

    constexpr int NH = MT / 64;
    ffrag acc[NH][8];
    #pragma unroll
    for (int mt = 0; mt < NH; ++mt)
        #pragma unroll
        for (int nt = 0; nt < 8; ++nt)
            #pragma unroll
            for (int e = 0; e < 4; ++e) acc[mt][nt][e] = 0.f;

    for (int k0 = 0; k0 < K; k0 += 32) {
        // A staging: MT rows x 32 cols bf16
        #pragma unroll
        for (int half = 0; half < NH; ++half) {
            int gm = m0 + half * 64 + amm;
            float f[8];
            #pragma unroll
            for (int e = 0; e < 8; ++e) {
                int gk = k0 + akc + e;
                f[e] = (gm < M && gk < K) ? Az[(size_t)gm * K + gk] : 0.f;
            }
            u32* dst = (u32*)&Ash[(half * 64 + amm) * 40 + akc];
            #pragma unroll
            for (int e = 0; e < 4; ++e) dst[e] = packbf(f[2 * e], f[2 * e + 1]);
        }
        if constexpr (LNF) {
            int gk = k0 + bkk;           // K == 96 exactly, always in range
            const float* src = xz + (size_t)gk * NPIX + n0;
            float gc = lng[gk], bc = lnb[gk];
            #pragma unroll
            for (int pass = 0; pass < 2; ++pass) {
                int nn = (bs0 + pass * 8) * 8;
                float4 f0 = *(const float4*)(src + nn);
                float4 f1 = *(const float4*)(src + nn + 4);
                float f[8] = {f0.x, f0.y, f0.z, f0.w, f1.x, f1.y, f1.z, f1.w};
                #pragma unroll
                for (int e = 0; e < 8; ++e) {
                    float nv = (f[e] - lmu[nn + e]) * linv[nn + e] * gc + bc;
                    Bsh[(nn + e) * 40 + bkk] = f2u16(nv);
                }
            }
        } else {
            int gk = k0 + bkk;
            bool ok = gk < K;
            const u16* src = Bz + (size_t)gk * NPIX + n0;
            #pragma unroll
            for (int pass = 0; pass < 2; ++pass) {
                int nn = (bs0 + pass * 8) * 8;
                if (ok) {
                    uint4 v = *(const uint4*)(src + nn);
                    Bsh[(nn + 0) * 40 + bkk] = (u16)(v.x & 0xffff);
                    Bsh[(nn + 1) * 40 + bkk] = (u16)(v.x >> 16);
                    Bsh[(nn + 2) * 40 + bkk] = (u16)(v.y & 0xffff);
                    Bsh[(nn + 3) * 40 + bkk] = (u16)(v.y >> 16);
                    Bsh[(nn + 4) * 40 + bkk] = (u16)(v.z & 0xffff);
                    Bsh[(nn + 5) * 40 + bkk] = (u16)(v.z >> 16);
                    Bsh[(nn + 6) * 40 + bkk] = (u16)(v.w & 0xffff);
                    Bsh[(nn + 7) * 40 + bkk] = (u16)(v.w >> 16);
                } else {
                    #pragma unroll
                    for (int e = 0; e < 8; ++e) Bsh[(nn + e) * 40 + bkk] = 0;
                }
            }
        }
        __syncthreads();
        bfrag af[NH];
        #pragma unroll
        for (int half = 0; half < NH; ++half)
            af[half] = *(const bfrag*)&Ash[(half * 64 + w * 16 + l15) * 40 + q * 8];
        #pragma unroll
        for (int nt = 0; nt < 8; ++nt) {
            bfrag bf = *(const bfrag*)&Bsh[(nt * 16 + l15) * 40 + q * 8];
            #pragma unroll
            for (int half = 0; half < NH; ++half)
                acc[half][nt] = __builtin_amdgcn_mfma_f32_16x16x32_bf16(af[half], bf, acc[half][nt], 0, 0, 0);
        }
        __syncthreads();
    }
    TOut* Cz = Cm + (size_t)blockIdx.z * strideC;
    const float* rz = res + (RES ? (size_t)blockIdx.z * strideC : 0);
    #pragma unroll
    for (int mt = 0; mt < NH; ++mt) {
        int mrow = m0 + mt * 64 + w * 16 + q * 4;
        #pragma unroll
        for (int nt = 0; nt < 8; ++nt) {
            int col = n0 + nt * 16 + l15;
            #pragma unroll
            for (int r = 0; r < 4; ++r) {
                int row = mrow + r;
                if (row < M) {
                    float v = acc[mt][nt][r];
                    if (RES) v += rz[(size_t)row * NPIX + col];
                    if constexpr (OFMT == 0) {
                        ((float*)Cz)[(size_t)row * NPIX + col] = v;
                    } else if constexpr (OFMT == 1) {
                        ((u16*)Cz)[(size_t)row * NPIX + col] = f2u16(v);
                    } else {
                        __half hh = __float2half(v);
                        ((u16*)Cz)[(size_t)row * NPIX + col] = __builtin_bit_cast(u16, hh);
                    }
                }
            }
        }
    }
}

// load a 1x10 window row (8 aligned + 2 halo) with zero padding (global memory)
__device__ __forceinline__ void load_row_zpad(const u16* ib, int iy, int x0, float a[10]) {
    if (iy < 0 || iy >= NW) {
        #pragma unroll
        for (int k = 0; k < 10; ++k) a[k] = 0.f;
        return;
    }
    const u16* rp = ib + iy * NW;
    uint4 v = *(const uint4*)(rp + x0);
    a[1]=bflo(v.x); a[2]=bfhi(v.x); a[3]=bflo(v.y); a[4]=bfhi(v.y);
    a[5]=bflo(v.z); a[6]=bfhi(v.z); a[7]=bflo(v.w); a[8]=bfhi(v.w);
    a[0] = (x0 > 0)   ? bfu(rp[x0 - 1]) : 0.f;
    a[9] = (x0 < 120) ? bfu(rp[x0 + 8]) : 0.f;
}

// ---------------- depthwise 3x3 (qkv), zero pad, 4 rows x 8 px/thread -------
// Fused qknorm: channels < 192 (q,k) accumulate sum-of-squares of the conv
// output (pre-bf16-rounding, sub-ulp diff) into sqsum[b*192+oc] via one
// atomicAdd per block (2 blocks/channel).
template <bool RELU>
__global__ __launch_bounds__(256) void dwconv3x3_kernel(
    const u16* __restrict__ in, const float* __restrict__ w,
    u16* __restrict__ out, int CHN, int ICN, int idiv,
    float* __restrict__ sqsum) {
    int id = blockIdx.x * 256 + threadIdx.x;   // 0..511
    int ty = id >> 4, tx = id & 15;
    int y0 = ty * 4, x0 = tx * 8;
    int b = blockIdx.y / CHN, oc = blockIdx.y % CHN;
    int ic = oc / idiv;
    const u16* ib = in + ((size_t)b * ICN + ic) * NPIX;
    float a[6][10];
    #pragma unroll
    for (int k = 0; k < 6; ++k) load_row_zpad(ib, y0 - 1 + k, x0, a[k]);
    const float* wr = w + (size_t)oc * 9;
    float w9[9];
    #pragma unroll
    for (int k = 0; k < 9; ++k) w9[k] = wr[k];
    u16* ob = out + ((size_t)b * CHN + oc) * NPIX + y0 * NW + x0;
    float s2 = 0.f;
    #pragma unroll
    for (int jr = 0; jr < 4; ++jr) {
        float o[8];
        #pragma unroll
        for (int j = 0; j < 8; ++j) {
            float s = 0.f;
            #pragma unroll
            for (int r = 0; r < 3; ++r)
                #pragma unroll
                for (int kx = 0; kx < 3; ++kx)
                    s += w9[r * 3 + kx] * a[jr + r][j + kx];
            o[j] = RELU ? fmaxf(s, 0.f) : s;
            s2 += o[j] * o[j];
        }
        *(uint4*)(ob + jr * NW) = pack8(o);
    }
    if (oc < 192) {   // block-uniform branch
        #pragma unroll
        for (int off = 32; off > 0; off >>= 1) s2 += __shfl_down(s2, off, 64);
        __shared__ float prt[4];
        int wid = threadIdx.x >> 6;
        if ((threadIdx.x & 63) == 0) prt[wid] = s2;
        __syncthreads();
        if (threadIdx.x == 0)
            atomicAdd(&sqsum[b * 192 + oc], prt[0] + prt[1] + prt[2] + prt[3]);
    }
}

// ---------------- attn dots via MFMA: attn[b,h] = q (12x16384) @ k^T ----------
// Grid (16 pixel-slices, NB*NHD). 4 waves/block, wave covers 256 px = 8
// chunks of 32. Fragment layout mirrors gemm1x1 (proven): lane l holds
// channel (l&15), pixels (l>>4)*8+0..7; D: i=(l>>4)*4+r, j=l&15.
// Channel pads 12..15 read adjacent valid rows; land only in discarded
// i,j >= 12. q,k each read exactly once (was 12x for k). Block-level LDS
// reduction then 144 atomicAdds (16-way contention per address).
__global__ __launch_bounds__(256) void attn_kernel(
    const u16* __restrict__ qkv2, float* __restrict__ attn_raw) {
    int wq = threadIdx.x >> 6, lane = threadIdx.x & 63;
    int bh = blockIdx.y;
    int b = bh / NHD, h = bh % NHD;
    const u16* qb = qkv2 + ((size_t)b * 288 + h * CHD) * NPIX;
    const u16* kb = qkv2 + ((size_t)b * 288 + 96 + h * CHD) * NPIX;
    int ch = lane & 15;
    int pxw = (blockIdx.x * 4 + wq) * 256 + ((lane >> 4) * 8);
    ffrag acc;
    #pragma unroll
    for (int e = 0; e < 4; ++e) acc[e] = 0.f;
    #pragma unroll
    for (int c = 0; c < 8; ++c) {
        int px = pxw + c * 32;
        bfrag aq = *(const bfrag*)(qb + (size_t)ch * NPIX + px);
        bfrag bk = *(const bfrag*)(kb + (size_t)ch * NPIX + px);
        acc = __builtin_amdgcn_mfma_f32_16x16x32_bf16(aq, bk, acc, 0, 0, 0);
    }
    __shared__ float red[4][64][4];
    #pragma unroll
    for (int r = 0; r < 4; ++r) red[wq][lane][r] = acc[r];
    __syncthreads();
    if (threadIdx.x < CHD * CHD) {
        int i = threadIdx.x / CHD, j = threadIdx.x % CHD;
        int l = ((i >> 2) << 4) | j;
        int r = i & 3;
        float s = red[0][l][r] + red[1][l][r] + red[2][l][r] + red[3][l][r];
        atomicAdd(&attn_raw[((size_t)bh * CHD + i) * CHD + j], s);
    }
}

// ---------------- STS + W-mix fused ----------------
// sclr holds raw per-channel sum-of-squares (from dwconv); convert to
// reciprocal norms in LDS, scale raw dots, thresholds, 4-way softmax mix
// -> attnc (LDS only), then W = proj @ attnc (av+proj fusion).
__global__ __launch_bounds__(256) void sts_kernel(
    const float* __restrict__ attn, const float* __restrict__ sclr,
    const float* __restrict__ temp, const float* __restrict__ tw,
    const float* __restrict__ w1, const float* __restrict__ b1,
    const float* __restrict__ w2, const float* __restrict__ b2,
    const float* __restrict__ proj_w, float* __restrict__ Wm) {
    int b = blockIdx.x;
    __shared__ float sat[NHD * CHD * CHD];
    __shared__ float sac[NHD * CHD * CHD];
    __shared__ float srs[192];
    __shared__ float pavg[NHD * CHD];
    __shared__ float avg[NHD];
    __shared__ float thr[4][NHD];
    if (threadIdx.x < 192) {
        float r = sclr[b * 192 + threadIdx.x];
        srs[threadIdx.x] = 1.f / fmaxf(sqrtf(r), 1e-12f);
    }
    __syncthreads();
    for (int idx = threadIdx.x; idx < NHD * CHD * CHD; idx += 256) {
        int h = idx / (CHD * CHD); int r = idx % (CHD * CHD);
        int i = r / CHD, j = r % CHD;
        sat[idx] = attn[(size_t)b * NHD * CHD * CHD + idx]
                 * srs[h * CHD + i] * srs[96 + h * CHD + j] * temp[h];
    }
    __syncthreads();
    if (threadIdx.x < NHD * CHD) {
        float s = 0.f;
        const float* row = sat + threadIdx.x * CHD;
        #pragma unroll
        for (int j = 0; j < CHD; ++j) s += fabsf(row[j]);
        pavg[threadIdx.x] = s;
    }
    __syncthreads();
    if (threadIdx.x < NHD) {
        float s = 0.f;
        #pragma unroll
        for (int i = 0; i < CHD; ++i) s += pavg[threadIdx.x * CHD + i];
        avg[threadIdx.x] = s * (1.f / (CHD * CHD));
    }
    __syncthreads();
    if (threadIdx.x < 4) {
        int s = threadIdx.x;
        float t1[NHD];
        for (int hp = 0; hp < NHD; ++hp) {
            float u = b1[s * NHD + hp];
            for (int h = 0; h < NHD; ++h) u += avg[h] * w1[s * 64 + hp * NHD + h];
            t1[hp] = fmaxf(u, 0.f);
        }
        for (int hp = 0; hp < NHD; ++hp) {
            float u = b2[s * NHD + hp];
            for (int h = 0; h < NHD; ++h) u += t1[h] * w2[s * 64 + hp * NHD + h];
            float gg = 1.f / (1.f + expf(-u));
            thr[s][hp] = avg[hp] * gg;
        }
    }
    __syncthreads();
    if (threadIdx.x < NHD * CHD) {
        int h = threadIdx.x / CHD, i = threadIdx.x % CHD;
        const float* arow = sat + (h * CHD + i) * CHD;
        float acc[CHD];
        #pragma unroll
        for (int j = 0; j < CHD; ++j) acc[j] = 0.f;
        for (int s = 0; s < 4; ++s) {
            float comp[CHD]; float m = -1e30f;
            #pragma unroll
            for (int j = 0; j < CHD; ++j) {
                float a = arow[j];
                float sg = (a > 0.f) ? 1.f : ((a < 0.f) ? -1.f : 0.f);
                float c = sg * fmaxf(fabsf(a) - thr[s][h], 0.f);
                comp[j] = c; m = fmaxf(m, c);
            }
            float sum = 0.f;
            #pragma unroll
            for (int j = 0; j < CHD; ++j) { comp[j] = expf(comp[j] - m); sum += comp[j]; }
            float wts2v = tw[s] / sum;
            #pragma unroll
            for (int j = 0; j < CHD; ++j) acc[j] += wts2v * comp[j];
        }
        for (int j = 0; j < CHD; ++j)
            sac[(h * CHD + i) * CHD + j] = acc[j];
    }
    __syncthreads();
    // W = proj @ attnc (head-block-diagonal): 36 outputs/thread x 12 fma
    float* Wb = Wm + (size_t)b * NC * NC;
    for (int idx = threadIdx.x; idx < NC * NC; idx += 256) {
        int m = idx / NC, col = idx % NC;
        int h = col / CHD, j = col % CHD;
        const float* pr = proj_w + m * NC + h * CHD;
        const float* ar = sac + h * CHD * CHD + j;
        float s = 0.f;
        #pragma unroll
        for (int i = 0; i < CHD; ++i) s += pr[i] * ar[i * CHD];
        Wb[idx] = s;
    }
}

// ---------------- launch ----------------
extern "C" void kernel_launch(void* const* d_in, const int* in_sizes, int n_in,
                              void* d_out, int out_size, void* d_ws, size_t ws_size,
                              hipStream_t stream) {
    const float* x       = (const float*)d_in[0];
    const float* norm1_w = (const float*)d_in[1];
    const float* norm1_b = (const float*)d_in[2];
    const float* qkv_w   = (const float*)d_in[3];
    const float* qkv_dw  = (const float*)d_in[4];
    const float* proj_w  = (const float*)d_in[5];
    const float* temp    = (const float*)d_in[6];
    const float* thw     = (const float*)d_in[7];
    const float* aw1     = (const float*)d_in[8];
    const float* ab1     = (const float*)d_in[9];
    const float* aw2     = (const float*)d_in[10];
    const float* ab2     = (const float*)d_in[11];
    const float* norm2_w = (const float*)d_in[12];
    const float* norm2_b = (const float*)d_in[13];
    const float* in_w    = (const float*)d_in[14];
    const float* main_w  = (const float*)d_in[15];
    const float* lp_w    = (const float*)d_in[16];
    const float* hp_w    = (const float*)d_in[17];
    const float* ld_w    = (const float*)d_in[18];
    const float* hd_w    = (const float*)d_in[19];
    const float* out_w   = (const float*)d_in[20];
    float* out = (float*)d_out;

    // ---- workspace layout ----
    char* ws = (char*)d_ws;
    float* x1    = (float*)(ws + 0);            // 12,582,912 fp32 residual stream
    u16*   qkv1  = (u16*)(ws + 18874368);       // 18,874,368 bf16 [2][288][NPIX]
    u16*   qkv2  = (u16*)(ws + 37748736);       // 18,874,368 bf16 [2][288][NPIX]
    float* scl   = (float*)(ws + 56623104);     // 1,536 B raw sum-of-squares
    float* attn  = (float*)(ws + 56624640);     // 9,216 B raw dots (scl+attn zeroed together)
    char*  F0    = ws + 56672256;
    // Wm (73,728 B): dead before cat(F0) is written; overlap is safe.
    float* Wm    = (float*)(ws + 56655872);
    const size_t S_full = 33423360;
    bool full = ws_size >= (size_t)56672256 + S_full;   // 90,095,616

    dim3 blk(256);
    // ---- attention half ----
    (void)hipMemsetAsync(scl, 0, 10752, stream);   // scl (1536B) + attn (9216B)
    gemm1x1_kernel<u16, false, 1, true, 128><<<dim3(128, 3, NB), blk, 0, stream>>>(
        nullptr, qkv_w, nullptr, qkv1, 288, 96, 0, (size_t)288 * NPIX, 0,
        x, norm1_w, norm1_b);                      // LN1 fused into B staging
    dwconv3x3_kernel<false><<<dim3(2, NB * 288), blk, 0, stream>>>(
        qkv1, qkv_dw, qkv2, 288, 288, 1, scl);     // + fused qk sum-of-squares
    attn_kernel<<<dim3(16, NB * NHD), blk, 0, stream>>>(qkv2, attn);
    sts_kernel<<<dim3(NB), blk, 0, stream>>>(attn, scl, temp, thw, aw1, ab1, aw2, ab2,
                                             proj_w, Wm);
    // x1 = x + W @ v   (av+proj fused; v = qkv2 channels 192..287)
    gemm1x1_kernel<float, true, 0, false, 64><<<dim3(128, 2, NB), blk, 0, stream>>>(
        qkv2 + (size_t)192 * NPIX, Wm, x, x1, 96, 96,
        (size_t)288 * NPIX, (size_t)NC * NPIX, (size_t)NC * NC,
        nullptr, nullptr, nullptr);
    // ---- FFN half ----
    if (full) {
        u16* yi  = qkv1;     // fp16, 33.4 MB spanning qkv1+qkv2 (dead now)
        u16* cat = (u16*)F0; // bf16
        gemm1x1_kernel<u16, false, 2, true, 128><<<dim3(128, 4, NB), blk, 0, stream>>>(
            nullptr, in_w, nullptr, yi, H2C, 96, 0, (size_t)H2C * NPIX, 0,
            x1, norm2_w, norm2_b);                 // LN2 fused into B staging
        ffnstream_kernel<<<dim3(4, HIDC, NB), dim3(64), 0, stream>>>(
            yi, main_w, lp_w, hp_w, ld_w, hd_w, cat);
        gemm1x1_kernel<float, true, 0, false, 64><<<dim3(128, 2, NB), blk, 0, stream>>>(
            cat, out_w, x1, out, 96, H2C, (size_t)H2C * NPIX, (size_t)NC * NPIX, 0,
            nullptr, nullptr, nullptr);
    } else {
        for (int b = 0; b < NB; ++b) {
            u16* yi  = qkv1;
            u16* cat = qkv2;
            gemm1x1_kernel<u16, false, 2, true, 128><<<dim3(128, 4, 1), blk, 0, stream>>>(
                nullptr, in_w, nullptr, yi, H2C, 96, 0, 0, 0,
                x1 + (size_t)b * NC * NPIX, norm2_w, norm2_b);
            ffnstream_kernel<<<dim3(4, HIDC, 1), dim3(64), 0, stream>>>(
                yi, main_w, lp_w, hp_w, ld_w, hd_w, cat);
            gemm1x1_kernel<float, true, 0, false, 64><<<dim3(128, 2, 1), blk, 0, stream>>>(
                cat, out_w, x1 + (size_t)b * NC * NPIX, out + (size_t)b * NC * NPIX,
                96, H2C, 0, 0, 0, nullptr, nullptr, nullptr);
        }
    }
}